// Round 14
// baseline (1044.017 us; speedup 1.0000x reference)
//
#include <hip/hip_runtime.h>

#define L 10

using bf16x8 = __attribute__((ext_vector_type(8))) __bf16;
using u16x8  = __attribute__((ext_vector_type(8))) unsigned short;
using f32x4  = __attribute__((ext_vector_type(4))) float;

__device__ __forceinline__ unsigned short f2bf(float f) {
  unsigned int u = __float_as_uint(f);
  u += 0x7FFFu + ((u >> 16) & 1u);          // RNE
  return (unsigned short)(u >> 16);
}
__device__ __forceinline__ float bf2f(unsigned short h) {
  return __uint_as_float(((unsigned int)h) << 16);
}

// ---------------------------------------------------------------------------
// Plaquette: single thread, exact fp32, matching JAX trunc-cast + python mod.
// ---------------------------------------------------------------------------
__global__ void plaq_kernel(const float* __restrict__ x,
                            const float* __restrict__ field,
                            float* __restrict__ out) {
  if (threadIdx.x != 0 || blockIdx.x != 0) return;
  int c[4];
#pragma unroll
  for (int i = 0; i < 4; ++i) {
    int v = (int)x[i];
    v %= L; if (v < 0) v += L;
    c[i] = v;
  }
  float S = 0.f;
  for (int mu = 0; mu < 4; ++mu)
    for (int nu = mu + 1; nu < 4; ++nu) {
      int p[4] = {c[0], c[1], c[2], c[3]};
      float l1 = field[((p[0]*L + p[1])*L + p[2])*4 + mu];
      p[mu] = (p[mu] + 1) % L;
      float l2 = field[((p[0]*L + p[1])*L + p[2])*4 + nu];
      p[nu] = (p[nu] + 1) % L;
      float l3 = field[((p[0]*L + p[1])*L + p[2])*4 + mu];
      float l4 = field[((c[0]*L + c[1])*L + c[2])*4 + nu];
      S += l1 + l2 - l3 - l4;
    }
  out[0] = expf(S);
}

// ---------------------------------------------------------------------------
// init heads: outWil[i] = wb3[0], outTop[i] = tb2[0]  (atomic bases)
// ---------------------------------------------------------------------------
__global__ void init_heads_kernel(float* __restrict__ outWil,
                                  float* __restrict__ outTop,
                                  const float* __restrict__ wb3,
                                  const float* __restrict__ tb2) {
  int i = blockIdx.x * blockDim.x + threadIdx.x;
  if (i < 16384) { outWil[i] = wb3[0]; outTop[i] = tb2[0]; }
}

// ---------------------------------------------------------------------------
// fc1: h = relu(x[16384,4] @ fw1[4,2048] + fb1) -> bf16.
// ---------------------------------------------------------------------------
__global__ void fc1_kernel(const float* __restrict__ x,
                           const float* __restrict__ fw1,
                           const float* __restrict__ fb1,
                           unsigned short* __restrict__ h) {
  const int N = 2048;
  int idx = blockIdx.x * blockDim.x + threadIdx.x;
  int m  = idx >> 8;
  int n0 = (idx & 255) * 8;
  float4 xv = *(const float4*)(x + (size_t)m * 4);
  unsigned short o[8];
#pragma unroll
  for (int j = 0; j < 8; ++j) {
    int n = n0 + j;
    float s = fb1[n] + xv.x * fw1[n] + xv.y * fw1[N + n]
                     + xv.z * fw1[2*N + n] + xv.w * fw1[3*N + n];
    o[j] = f2bf(fmaxf(s, 0.f));
  }
  *(u16x8*)(h + (size_t)m * N + n0) = *(const u16x8*)o;
}

// ---------------------------------------------------------------------------
// Weight transpose+convert: W[K][N] f32 -> WT[N][K] bf16.
// ---------------------------------------------------------------------------
__global__ void transpose_bf16_kernel(const float* __restrict__ W,
                                      unsigned short* __restrict__ WT,
                                      int K, int N) {
  __shared__ float tile[32][33];
  int n0 = blockIdx.x * 32, k0 = blockIdx.y * 32;
  int tx = threadIdx.x, ty = threadIdx.y;   // 32 x 8
#pragma unroll
  for (int i = 0; i < 32; i += 8)
    tile[ty + i][tx] = W[(size_t)(k0 + ty + i) * N + n0 + tx];
  __syncthreads();
#pragma unroll
  for (int i = 0; i < 32; i += 8)
    WT[(size_t)(n0 + ty + i) * K + k0 + tx] = f2bf(tile[tx][ty + i]);
}

// ---------------------------------------------------------------------------
// Elementwise f32 -> bf16 cast (natural layout), 8 elems/thread.
// ---------------------------------------------------------------------------
__global__ void cast_bf16_kernel(const float* __restrict__ in,
                                 unsigned short* __restrict__ out) {
  size_t i = ((size_t)blockIdx.x * blockDim.x + threadIdx.x) * 8;
  unsigned short o[8];
#pragma unroll
  for (int j = 0; j < 8; ++j) o[j] = f2bf(in[i + j]);
  *(u16x8*)(out + i) = *(const u16x8*)o;
}

// ---------------------------------------------------------------------------
// biascat: out[0:4096] = fb2; out[4096+m] = (m<2048?wb1[m]:tb1[m-2048])
//                                + sum_j catT[m][j]*fb2[j]    (wave per row)
// ---------------------------------------------------------------------------
__global__ void biascat_kernel(const unsigned short* __restrict__ catT,
                               const float* __restrict__ fb2,
                               const float* __restrict__ wb1,
                               const float* __restrict__ tb1,
                               float* __restrict__ out) {
  int w    = blockIdx.x * 4 + (threadIdx.x >> 6);   // 0..8191
  int lane = threadIdx.x & 63;
  if (w < 4096) { if (lane == 0) out[w] = fb2[w]; return; }
  int m = w - 4096;
  const unsigned short* row = catT + (size_t)m * 4096;
  float s = 0.f;
  for (int k = lane * 8; k < 4096; k += 512) {
    u16x8 v = *(const u16x8*)(row + k);
#pragma unroll
    for (int j = 0; j < 8; ++j) s += bf2f(v[j]) * fb2[k + j];
  }
#pragma unroll
  for (int off = 32; off; off >>= 1) s += __shfl_down(s, off);
  if (lane == 0) out[w] = s + (m < 2048 ? wb1[m] : tb1[m - 2048]);
}

#define GLL(gp, lp)                                                            \
  __builtin_amdgcn_global_load_lds(                                            \
      (const __attribute__((address_space(1))) unsigned int*)(gp),             \
      (__attribute__((address_space(3))) unsigned int*)(lp), 16, 0, 0)

#define DSREAD(dst, addr)                                                      \
  asm volatile("ds_read_b128 %0, %1" : "=v"(dst) : "v"(addr))

#define LGKM(n)                                                                \
  do { asm volatile("s_waitcnt lgkmcnt(" #n ")" ::: "memory");                 \
       __builtin_amdgcn_sched_barrier(0); } while (0)

#define FENCE() asm volatile("" ::: "memory")

extern __shared__ char lds_raw[];

// ---------------------------------------------------------------------------
// 128x128 bf16 MFMA GEMM with r5 counted schedule, ring-4 16KB slots (64KB,
// 2 blocks/CU). Raw bf16 out (W2catT producer). 4 waves (2Mx2N).
// ---------------------------------------------------------------------------
__global__ __launch_bounds__(256)
void gemm128f_kernel(const unsigned short* __restrict__ A,
                     const unsigned short* __restrict__ BT,
                     unsigned short* __restrict__ outB,
                     int N, int K, int gmx) {
  const int NT = K >> 5;

  const int nwg = gridDim.x;
  const int q = nwg >> 3, r = nwg & 7;
  const int xcd = blockIdx.x & 7, lid = blockIdx.x >> 3;
  const int wg2 = (xcd < r ? xcd * (q + 1) : r * (q + 1) + (xcd - r) * q) + lid;
  const int bm = wg2 % gmx, bn = wg2 / gmx;

  const int tid  = threadIdx.x;
  const int wid  = tid >> 6, lane = tid & 63;
  const int wr   = wid >> 1, wc = wid & 1;
  const int lr   = lane & 15, lg = lane >> 4;

  const int srow = tid >> 2;
  const int scol = ((tid & 3) ^ ((tid >> 3) & 3)) * 8;
  const unsigned short* agp0 = A  + (size_t)(bm * 128 + srow) * K + scol;
  const unsigned short* agp1 = agp0 + (size_t)64 * K;
  const unsigned short* bgp0 = BT + (size_t)(bn * 128 + srow) * K + scol;
  const unsigned short* bgp1 = bgp0 + (size_t)64 * K;

  const int chunk = lg ^ ((lr >> 1) & 3);
  const unsigned ldsbase = (unsigned)(uintptr_t)&lds_raw[0];
  const unsigned aoff = (unsigned)((wr * 64 + lr) * 64 + chunk * 16);
  const unsigned boff = (unsigned)(8192 + (wc * 64 + lr) * 64 + chunk * 16);

  f32x4 acc[4][4];
#pragma unroll
  for (int m = 0; m < 4; ++m)
#pragma unroll
    for (int n = 0; n < 4; ++n) acc[m][n] = (f32x4)0.f;

#define STAGE_A(tt) do { unsigned so = (unsigned)(((tt) & 3) << 14);           \
    GLL(agp0 + (size_t)(tt) * 32, lds_raw + so + tid * 16);                    \
    GLL(agp1 + (size_t)(tt) * 32, lds_raw + so + 4096 + tid * 16); } while (0)
#define STAGE_B(tt) do { unsigned so = (unsigned)(((tt) & 3) << 14);           \
    GLL(bgp0 + (size_t)(tt) * 32, lds_raw + so + 8192 + tid * 16);             \
    GLL(bgp1 + (size_t)(tt) * 32, lds_raw + so + 12288 + tid * 16); } while (0)

  STAGE_A(0); STAGE_B(0); STAGE_A(1); STAGE_B(1); STAGE_A(2); STAGE_B(2);

  for (int t = 0; t < NT; ++t) {
    const int rem = NT - 1 - t;
    if (rem >= 2)      asm volatile("s_waitcnt vmcnt(8)" ::: "memory");
    else if (rem == 1) asm volatile("s_waitcnt vmcnt(4)" ::: "memory");
    else               asm volatile("s_waitcnt vmcnt(0)" ::: "memory");
    FENCE(); __builtin_amdgcn_s_barrier(); FENCE();
    __builtin_amdgcn_sched_barrier(0);

    if (t + 3 < NT) { STAGE_A(t + 3); STAGE_B(t + 3); }

    const unsigned sbase = ldsbase + (unsigned)((t & 3) << 14);
    u16x8 b[4], a[4];
    DSREAD(b[0], sbase + boff);
    DSREAD(b[1], sbase + boff + 1024);
    DSREAD(b[2], sbase + boff + 2048);
    DSREAD(b[3], sbase + boff + 3072);
    DSREAD(a[0], sbase + aoff);
    DSREAD(a[1], sbase + aoff + 1024);
    DSREAD(a[2], sbase + aoff + 2048);
    DSREAD(a[3], sbase + aoff + 3072);

    __builtin_amdgcn_s_setprio(1);
#define CLUSTER(m, g)                                                          \
    LGKM(g);                                                                   \
    acc[m][0] = __builtin_amdgcn_mfma_f32_16x16x32_bf16(                       \
        __builtin_bit_cast(bf16x8, a[m]), __builtin_bit_cast(bf16x8, b[0]),    \
        acc[m][0], 0, 0, 0);                                                   \
    acc[m][1] = __builtin_amdgcn_mfma_f32_16x16x32_bf16(                       \
        __builtin_bit_cast(bf16x8, a[m]), __builtin_bit_cast(bf16x8, b[1]),    \
        acc[m][1], 0, 0, 0);                                                   \
    acc[m][2] = __builtin_amdgcn_mfma_f32_16x16x32_bf16(                       \
        __builtin_bit_cast(bf16x8, a[m]), __builtin_bit_cast(bf16x8, b[2]),    \
        acc[m][2], 0, 0, 0);                                                   \
    acc[m][3] = __builtin_amdgcn_mfma_f32_16x16x32_bf16(                       \
        __builtin_bit_cast(bf16x8, a[m]), __builtin_bit_cast(bf16x8, b[3]),    \
        acc[m][3], 0, 0, 0)

    CLUSTER(0, 3);
    CLUSTER(1, 2);
    CLUSTER(2, 1);
    CLUSTER(3, 0);
#undef CLUSTER
    __builtin_amdgcn_s_setprio(0);
    __builtin_amdgcn_sched_barrier(0);
  }
#undef STAGE_A
#undef STAGE_B

  const int rowBase = bm * 128 + wr * 64 + lg * 4;
  const int colBase = bn * 128 + wc * 64 + lr;
#pragma unroll
  for (int n = 0; n < 4; ++n) {
    int col = colBase + n * 16;
#pragma unroll
    for (int m = 0; m < 4; ++m) {
      int row = rowBase + m * 16;
#pragma unroll
      for (int j = 0; j < 4; ++j)
        outB[(size_t)(row + j) * N + col] = f2bf(acc[m][n][j]);
    }
  }
}

// ---------------------------------------------------------------------------
// 128x128 bf16 MFMA GEMM, OCCUPANCY build: ring-3 of 16KB slots (48KB dyn
// LDS -> 3 blocks/CU), acc 4x4 (64 VGPR) -> total ~120 VGPR -> 12 waves/CU.
// r5 counted schedule (vmcnt(4) gate, zero-conflict swizzle, lgkm clusters,
// setprio, T1 XCD swizzle). 4 waves (2Mx2N), 64x64 per wave.
// Three-way epilogue (r12): f32+bias / relu bf16 / fused head (hvec dot +
// atomicAdd). A row stride = lda.
// ---------------------------------------------------------------------------
__global__ __launch_bounds__(256)
void gemm128x_kernel(const unsigned short* __restrict__ A,
                     const unsigned short* __restrict__ BT,
                     const float* __restrict__ bias,
                     float* __restrict__ outF,
                     unsigned short* __restrict__ outB,
                     const float* __restrict__ hvec,
                     float* __restrict__ hout,
                     int lda, int K, int NF, int NB,
                     int nFtiles, int nHtiles, int gmx) {
  const int NT = K >> 5;

  const int nwg = gridDim.x;
  const int q = nwg >> 3, r = nwg & 7;
  const int xcd = blockIdx.x & 7, lid = blockIdx.x >> 3;
  const int wg2 = (xcd < r ? xcd * (q + 1) : r * (q + 1) + (xcd - r) * q) + lid;
  const int bm = wg2 % gmx, bn = wg2 / gmx;

  const int tid  = threadIdx.x;
  const int wid  = tid >> 6, lane = tid & 63;
  const int wr   = wid >> 1, wc = wid & 1;
  const int lr   = lane & 15, lg = lane >> 4;

  const int srow = tid >> 2;
  const int scol = ((tid & 3) ^ ((tid >> 3) & 3)) * 8;
  const unsigned short* agp0 = A  + (size_t)(bm * 128 + srow) * lda + scol;
  const unsigned short* agp1 = agp0 + (size_t)64 * lda;
  const unsigned short* bgp0 = BT + (size_t)(bn * 128 + srow) * K + scol;
  const unsigned short* bgp1 = bgp0 + (size_t)64 * K;

  const int chunk = lg ^ ((lr >> 1) & 3);
  const unsigned ldsbase = (unsigned)(uintptr_t)&lds_raw[0];
  const unsigned aoff = (unsigned)((wr * 64 + lr) * 64 + chunk * 16);
  const unsigned boff = (unsigned)(8192 + (wc * 64 + lr) * 64 + chunk * 16);

  f32x4 acc[4][4];
#pragma unroll
  for (int m = 0; m < 4; ++m)
#pragma unroll
    for (int n = 0; n < 4; ++n) acc[m][n] = (f32x4)0.f;

  // ring-3: slot(t) = t % 3 (16KB each)
#define SLOT(tt) ((unsigned)(((tt) % 3) * 16384))
#define STAGE_A(tt) do { unsigned so = SLOT(tt);                               \
    GLL(agp0 + (size_t)(tt) * 32, lds_raw + so + tid * 16);                    \
    GLL(agp1 + (size_t)(tt) * 32, lds_raw + so + 4096 + tid * 16); } while (0)
#define STAGE_B(tt) do { unsigned so = SLOT(tt);                               \
    GLL(bgp0 + (size_t)(tt) * 32, lds_raw + so + 8192 + tid * 16);             \
    GLL(bgp1 + (size_t)(tt) * 32, lds_raw + so + 12288 + tid * 16); } while (0)

  // prologue: tiles 0,1 staged (8 loads in flight)
  STAGE_A(0); STAGE_B(0); STAGE_A(1); STAGE_B(1);

  for (int t = 0; t < NT; ++t) {
    const int rem = NT - 1 - t;
    // gate tile t's 4 loads; keep t+1's 4 in flight
    if (rem >= 1) asm volatile("s_waitcnt vmcnt(4)" ::: "memory");
    else          asm volatile("s_waitcnt vmcnt(0)" ::: "memory");
    FENCE(); __builtin_amdgcn_s_barrier(); FENCE();
    __builtin_amdgcn_sched_barrier(0);

    // stage t+2 into slot (t-1)%3: reads of t-1 retired (final LGKM(0))
    // before every wave passed barrier(t) -> race-free
    if (t + 2 < NT) { STAGE_A(t + 2); STAGE_B(t + 2); }

    const unsigned sbase = ldsbase + SLOT(t);
    u16x8 b[4], a[4];
    DSREAD(b[0], sbase + boff);
    DSREAD(b[1], sbase + boff + 1024);
    DSREAD(b[2], sbase + boff + 2048);
    DSREAD(b[3], sbase + boff + 3072);
    DSREAD(a[0], sbase + aoff);
    DSREAD(a[1], sbase + aoff + 1024);
    DSREAD(a[2], sbase + aoff + 2048);
    DSREAD(a[3], sbase + aoff + 3072);

    __builtin_amdgcn_s_setprio(1);
#define CLUSTER(m, g)                                                          \
    LGKM(g);                                                                   \
    acc[m][0] = __builtin_amdgcn_mfma_f32_16x16x32_bf16(                       \
        __builtin_bit_cast(bf16x8, a[m]), __builtin_bit_cast(bf16x8, b[0]),    \
        acc[m][0], 0, 0, 0);                                                   \
    acc[m][1] = __builtin_amdgcn_mfma_f32_16x16x32_bf16(                       \
        __builtin_bit_cast(bf16x8, a[m]), __builtin_bit_cast(bf16x8, b[1]),    \
        acc[m][1], 0, 0, 0);                                                   \
    acc[m][2] = __builtin_amdgcn_mfma_f32_16x16x32_bf16(                       \
        __builtin_bit_cast(bf16x8, a[m]), __builtin_bit_cast(bf16x8, b[2]),    \
        acc[m][2], 0, 0, 0);                                                   \
    acc[m][3] = __builtin_amdgcn_mfma_f32_16x16x32_bf16(                       \
        __builtin_bit_cast(bf16x8, a[m]), __builtin_bit_cast(bf16x8, b[3]),    \
        acc[m][3], 0, 0, 0)

    CLUSTER(0, 3);
    CLUSTER(1, 2);
    CLUSTER(2, 1);
    CLUSTER(3, 0);
#undef CLUSTER
    __builtin_amdgcn_s_setprio(0);
    __builtin_amdgcn_sched_barrier(0);
  }
#undef SLOT
#undef STAGE_A
#undef STAGE_B

  const int rowBase = bm * 128 + wr * 64 + lg * 4;
  const int colBase = bn * 128 + wc * 64 + lr;
  if (bn < nFtiles) {
#pragma unroll
    for (int n = 0; n < 4; ++n) {
      int col = colBase + n * 16;
      float bv = bias[col];
#pragma unroll
      for (int m = 0; m < 4; ++m) {
        int row = rowBase + m * 16;
#pragma unroll
        for (int j = 0; j < 4; ++j)
          __builtin_nontemporal_store(acc[m][n][j] + bv,
                                      &outF[(size_t)(row + j) * NF + col]);
      }
    }
  } else if (bn < nHtiles) {
    const int colB = colBase - nFtiles * 128;
#pragma unroll
    for (int n = 0; n < 4; ++n) {
      int col = colB + n * 16;
      float bv = bias[colBase + n * 16];
#pragma unroll
      for (int m = 0; m < 4; ++m) {
        int row = rowBase + m * 16;
#pragma unroll
        for (int j = 0; j < 4; ++j)
          outB[(size_t)(row + j) * NB + col] = f2bf(fmaxf(acc[m][n][j] + bv, 0.f));
      }
    }
  } else {
    // fused head: hout[row] += sum_col relu(C+bias)*hvec[col]
    const int hcol0 = colBase - nHtiles * 128;
    float bv[4], hv[4];
#pragma unroll
    for (int n = 0; n < 4; ++n) {
      bv[n] = bias[colBase + n * 16];
      hv[n] = hvec[hcol0 + n * 16];
    }
#pragma unroll
    for (int m = 0; m < 4; ++m) {
#pragma unroll
      for (int j = 0; j < 4; ++j) {
        float s = 0.f;
#pragma unroll
        for (int n = 0; n < 4; ++n)
          s += fmaxf(acc[m][n][j] + bv[n], 0.f) * hv[n];
        s += __shfl_xor(s, 1);
        s += __shfl_xor(s, 2);
        s += __shfl_xor(s, 4);
        s += __shfl_xor(s, 8);
        if (lr == 0)
          atomicAdd(&hout[rowBase + m * 16 + j], s);
      }
    }
  }
}

// ---------------------------------------------------------------------------
extern "C" void kernel_launch(void* const* d_in, const int* in_sizes, int n_in,
                              void* d_out, int out_size, void* d_ws, size_t ws_size,
                              hipStream_t stream) {
  const float* x     = (const float*)d_in[0];
  const float* field = (const float*)d_in[1];
  const float* fw1   = (const float*)d_in[2];
  const float* fb1   = (const float*)d_in[3];
  const float* fw2   = (const float*)d_in[4];
  const float* fb2   = (const float*)d_in[5];
  const float* ww1   = (const float*)d_in[6];
  const float* wb1   = (const float*)d_in[7];
  const float* ww2   = (const float*)d_in[8];
  const float* wb2   = (const float*)d_in[9];
  const float* ww3   = (const float*)d_in[10];
  const float* wb3   = (const float*)d_in[11];
  const float* tw1   = (const float*)d_in[12];
  const float* tb1   = (const float*)d_in[13];
  const float* tw2   = (const float*)d_in[14];
  const float* tb2   = (const float*)d_in[15];

  const int M = 16384;
  float* outF    = (float*)d_out;                  // field_output [16384,4096]
  float* outWil  = outF + (size_t)M * 4096;
  float* outTop  = outWil + M;
  float* outPlaq = outTop + M;

  char* ws = (char*)d_ws;
  const size_t MB = 1048576;
  unsigned short* hbuf    = (unsigned short*)(ws);              // [16384,2048] 64MB
  unsigned short* catbuf  = (unsigned short*)(ws + 64  * MB);   // [16384,2048] 64MB (w1)
  unsigned short* catT    = (unsigned short*)(ws + 192 * MB);   // [4096,4096]  32MB
  unsigned short* fw2T    = (unsigned short*)(ws + 224 * MB);   // [4096,2048]  16MB  \ contiguous =
  unsigned short* W2catT  = (unsigned short*)(ws + 240 * MB);   // [4096,2048]  16MB  / BTcat [8192,2048]
  unsigned short* BTcat   = fw2T;
  unsigned short* fw2bf   = (unsigned short*)(ws + 256 * MB);   // [2048,4096]  16MB
  unsigned short* ww2T    = (unsigned short*)(ws + 272 * MB);   // [1024,2048]  4MB
  float*          biascat = (float*)(ws + 276 * MB);            // [8192] 32KB

  const int SMEM128 = 65536; // gemm128f: ring-4 of 16KB -> 2 blocks/CU
  (void)hipFuncSetAttribute((const void*)gemm128f_kernel,
                            hipFuncAttributeMaxDynamicSharedMemorySize, SMEM128);
  const int SMEMX = 49152;   // gemm128x: ring-3 of 16KB -> 3 blocks/CU
  (void)hipFuncSetAttribute((const void*)gemm128x_kernel,
                            hipFuncAttributeMaxDynamicSharedMemorySize, SMEMX);

  // independent prep
  hipLaunchKernelGGL(plaq_kernel, dim3(1), dim3(64), 0, stream, x, field, outPlaq);
  hipLaunchKernelGGL(init_heads_kernel, dim3(64), dim3(256), 0, stream,
                     outWil, outTop, wb3, tb2);
  hipLaunchKernelGGL(fc1_kernel, dim3(16384), dim3(256), 0, stream, x, fw1, fb1, hbuf);
  hipLaunchKernelGGL(transpose_bf16_kernel, dim3(128, 64), dim3(32, 8), 0, stream,
                     fw2, fw2T, 2048, 4096);
  hipLaunchKernelGGL(cast_bf16_kernel, dim3(4096), dim3(256), 0, stream, fw2, fw2bf);
  hipLaunchKernelGGL(transpose_bf16_kernel, dim3(64, 128), dim3(32, 8), 0, stream,
                     ww1, catT, 4096, 2048);
  hipLaunchKernelGGL(transpose_bf16_kernel, dim3(64, 128), dim3(32, 8), 0, stream,
                     tw1, catT + (size_t)2048 * 4096, 4096, 2048);
  hipLaunchKernelGGL(transpose_bf16_kernel, dim3(32, 64), dim3(32, 8), 0, stream,
                     ww2, ww2T, 2048, 1024);
  hipLaunchKernelGGL(biascat_kernel, dim3(2048), dim3(256), 0, stream,
                     catT, fb2, wb1, tb1, biascat);

  // W2catT[n][k] = sum_j catT[n][j] * fw2bf[k][j]   (M=4096, N=2048, K=4096)
  hipLaunchKernelGGL(gemm128f_kernel, dim3(512), dim3(256), SMEM128, stream,
                     catT, fw2bf, W2catT, 2048, 4096, 32);

  // fused: C = h @ [fw2 | W2cat] + biascat   (M=16384, N=8192, K=2048)
  //   bn<32: field_output f32; 32<=bn<48: w1 relu bf16 (NB=2048);
  //   bn>=48: topology head fused (tw2 dot + atomicAdd outTop)
  hipLaunchKernelGGL(gemm128x_kernel, dim3(128 * 64), dim3(256), SMEMX, stream,
                     hbuf, BTcat, biascat, outF, catbuf, tw2, outTop,
                     2048, 2048, 4096, 2048, 32, 48, 128);

  // wilson: w2 = relu(w1 @ ww2 + wb2); outWil += w2 @ ww3  (all head blocks)
  hipLaunchKernelGGL(gemm128x_kernel, dim3(128 * 8), dim3(256), SMEMX, stream,
                     catbuf, ww2T, wb2, (float*)nullptr, (unsigned short*)nullptr,
                     ww3, outWil,
                     2048, 2048, 0, 0, 0, 0, 128);

  (void)in_sizes; (void)n_in; (void)out_size; (void)ws_size;
}

// Round 15
// 864.837 us; speedup vs baseline: 1.2072x; 1.2072x over previous
//
#include <hip/hip_runtime.h>

#define L 10

using bf16x8 = __attribute__((ext_vector_type(8))) __bf16;
using u16x8  = __attribute__((ext_vector_type(8))) unsigned short;
using f32x4  = __attribute__((ext_vector_type(4))) float;

__device__ __forceinline__ unsigned short f2bf(float f) {
  unsigned int u = __float_as_uint(f);
  u += 0x7FFFu + ((u >> 16) & 1u);          // RNE
  return (unsigned short)(u >> 16);
}
__device__ __forceinline__ float bf2f(unsigned short h) {
  return __uint_as_float(((unsigned int)h) << 16);
}

// ---------------------------------------------------------------------------
// Merged prep kernel — one launch replaces 7:
//   role by blockIdx.x range (whole block per role -> no divergence):
//   [0,16384)            fc1: h = relu(x @ fw1 + fb1) -> bf16
//   [16384,24576)        transpose fw2   [2048,4096] -> fw2T
//   [24576,32768)        transpose ww1   [4096,2048] -> catT[0:2048]
//   [32768,40960)        transpose tw1   [4096,2048] -> catT[2048:4096]
//   [40960,43008)        transpose ww2   [2048,1024] -> ww2T
//   [43008,47104)        cast fw2 f32 -> bf16 (natural layout)
//   [47104,47168)        init heads: outWil=wb3, outTop=tb2
//   47168                plaquette
// ---------------------------------------------------------------------------
__global__ void prep_kernel(const float* __restrict__ x,
                            const float* __restrict__ field,
                            const float* __restrict__ fw1,
                            const float* __restrict__ fb1,
                            const float* __restrict__ fw2,
                            const float* __restrict__ ww1,
                            const float* __restrict__ tw1,
                            const float* __restrict__ ww2,
                            const float* __restrict__ wb3,
                            const float* __restrict__ tb2,
                            unsigned short* __restrict__ hbuf,
                            unsigned short* __restrict__ fw2T,
                            unsigned short* __restrict__ catT,
                            unsigned short* __restrict__ ww2T,
                            unsigned short* __restrict__ fw2bf,
                            float* __restrict__ outWil,
                            float* __restrict__ outTop,
                            float* __restrict__ outPlaq) {
  __shared__ float tile[32][33];
  const int b   = blockIdx.x;
  const int tid = threadIdx.x;

  if (b < 16384) {                       // ---- fc1 ----
    const int N = 2048;
    int m  = b;
    int n0 = tid * 8;
    float4 xv = *(const float4*)(x + (size_t)m * 4);
    unsigned short o[8];
#pragma unroll
    for (int j = 0; j < 8; ++j) {
      int n = n0 + j;
      float s = fb1[n] + xv.x * fw1[n] + xv.y * fw1[N + n]
                       + xv.z * fw1[2*N + n] + xv.w * fw1[3*N + n];
      o[j] = f2bf(fmaxf(s, 0.f));
    }
    *(u16x8*)(hbuf + (size_t)m * N + n0) = *(const u16x8*)o;
    return;
  }

  const float* W = nullptr; unsigned short* WT = nullptr;
  int K = 0, N = 0, bx = 0, by = 0;
  if (b < 24576)      { int b2 = b - 16384; W = fw2; WT = fw2T; K = 2048; N = 4096; bx = b2 % 128; by = b2 / 128; }
  else if (b < 32768) { int b2 = b - 24576; W = ww1; WT = catT; K = 4096; N = 2048; bx = b2 % 64;  by = b2 / 64;  }
  else if (b < 40960) { int b2 = b - 32768; W = tw1; WT = catT + (size_t)2048 * 4096; K = 4096; N = 2048; bx = b2 % 64; by = b2 / 64; }
  else if (b < 43008) { int b2 = b - 40960; W = ww2; WT = ww2T; K = 2048; N = 1024; bx = b2 % 32;  by = b2 / 32;  }

  if (W) {                               // ---- transpose+convert ----
    int tx = tid & 31, ty = tid >> 5;    // 32 x 8
    int n0 = bx * 32, k0 = by * 32;
#pragma unroll
    for (int i = 0; i < 32; i += 8)
      tile[ty + i][tx] = W[(size_t)(k0 + ty + i) * N + n0 + tx];
    __syncthreads();
#pragma unroll
    for (int i = 0; i < 32; i += 8)
      WT[(size_t)(n0 + ty + i) * K + k0 + tx] = f2bf(tile[tx][ty + i]);
    return;
  }

  if (b < 47104) {                       // ---- cast fw2 -> bf16 ----
    size_t i = ((size_t)(b - 43008) * 256 + tid) * 8;
    unsigned short o[8];
#pragma unroll
    for (int j = 0; j < 8; ++j) o[j] = f2bf(fw2[i + j]);
    *(u16x8*)(fw2bf + i) = *(const u16x8*)o;
    return;
  }

  if (b < 47168) {                       // ---- init heads ----
    int i = (b - 47104) * 256 + tid;
    outWil[i] = wb3[0];
    outTop[i] = tb2[0];
    return;
  }

  // ---- plaquette (b == 47168) ----
  if (tid != 0) return;
  int c[4];
#pragma unroll
  for (int i = 0; i < 4; ++i) {
    int v = (int)x[i];
    v %= L; if (v < 0) v += L;
    c[i] = v;
  }
  float S = 0.f;
  for (int mu = 0; mu < 4; ++mu)
    for (int nu = mu + 1; nu < 4; ++nu) {
      int p[4] = {c[0], c[1], c[2], c[3]};
      float l1 = field[((p[0]*L + p[1])*L + p[2])*4 + mu];
      p[mu] = (p[mu] + 1) % L;
      float l2 = field[((p[0]*L + p[1])*L + p[2])*4 + nu];
      p[nu] = (p[nu] + 1) % L;
      float l3 = field[((p[0]*L + p[1])*L + p[2])*4 + mu];
      float l4 = field[((c[0]*L + c[1])*L + c[2])*4 + nu];
      S += l1 + l2 - l3 - l4;
    }
  outPlaq[0] = expf(S);
}

// ---------------------------------------------------------------------------
// biascat: out[0:4096] = fb2; out[4096+m] = (m<2048?wb1[m]:tb1[m-2048])
//                                + sum_j catT[m][j]*fb2[j]    (wave per row)
// ---------------------------------------------------------------------------
__global__ void biascat_kernel(const unsigned short* __restrict__ catT,
                               const float* __restrict__ fb2,
                               const float* __restrict__ wb1,
                               const float* __restrict__ tb1,
                               float* __restrict__ out) {
  int w    = blockIdx.x * 4 + (threadIdx.x >> 6);   // 0..8191
  int lane = threadIdx.x & 63;
  if (w < 4096) { if (lane == 0) out[w] = fb2[w]; return; }
  int m = w - 4096;
  const unsigned short* row = catT + (size_t)m * 4096;
  float s = 0.f;
  for (int k = lane * 8; k < 4096; k += 512) {
    u16x8 v = *(const u16x8*)(row + k);
#pragma unroll
    for (int j = 0; j < 8; ++j) s += bf2f(v[j]) * fb2[k + j];
  }
#pragma unroll
  for (int off = 32; off; off >>= 1) s += __shfl_down(s, off);
  if (lane == 0) out[w] = s + (m < 2048 ? wb1[m] : tb1[m - 2048]);
}

#define GLL(gp, lp)                                                            \
  __builtin_amdgcn_global_load_lds(                                            \
      (const __attribute__((address_space(1))) unsigned int*)(gp),             \
      (__attribute__((address_space(3))) unsigned int*)(lp), 16, 0, 0)

#define DSREAD(dst, addr)                                                      \
  asm volatile("ds_read_b128 %0, %1" : "=v"(dst) : "v"(addr))

#define LGKM(n)                                                                \
  do { asm volatile("s_waitcnt lgkmcnt(" #n ")" ::: "memory");                 \
       __builtin_amdgcn_sched_barrier(0); } while (0)

#define FENCE() asm volatile("" ::: "memory")

extern __shared__ char lds_raw[];

// ---------------------------------------------------------------------------
// 128x128 bf16 MFMA GEMM with r5 counted schedule, ring-4 16KB slots (64KB,
// 2 blocks/CU). Raw bf16 out (W2catT producer). 4 waves (2Mx2N).
// ---------------------------------------------------------------------------
__global__ __launch_bounds__(256)
void gemm128f_kernel(const unsigned short* __restrict__ A,
                     const unsigned short* __restrict__ BT,
                     unsigned short* __restrict__ outB,
                     int N, int K, int gmx) {
  const int NT = K >> 5;

  const int nwg = gridDim.x;
  const int q = nwg >> 3, r = nwg & 7;
  const int xcd = blockIdx.x & 7, lid = blockIdx.x >> 3;
  const int wg2 = (xcd < r ? xcd * (q + 1) : r * (q + 1) + (xcd - r) * q) + lid;
  const int bm = wg2 % gmx, bn = wg2 / gmx;

  const int tid  = threadIdx.x;
  const int wid  = tid >> 6, lane = tid & 63;
  const int wr   = wid >> 1, wc = wid & 1;
  const int lr   = lane & 15, lg = lane >> 4;

  const int srow = tid >> 2;
  const int scol = ((tid & 3) ^ ((tid >> 3) & 3)) * 8;
  const unsigned short* agp0 = A  + (size_t)(bm * 128 + srow) * K + scol;
  const unsigned short* agp1 = agp0 + (size_t)64 * K;
  const unsigned short* bgp0 = BT + (size_t)(bn * 128 + srow) * K + scol;
  const unsigned short* bgp1 = bgp0 + (size_t)64 * K;

  const int chunk = lg ^ ((lr >> 1) & 3);
  const unsigned ldsbase = (unsigned)(uintptr_t)&lds_raw[0];
  const unsigned aoff = (unsigned)((wr * 64 + lr) * 64 + chunk * 16);
  const unsigned boff = (unsigned)(8192 + (wc * 64 + lr) * 64 + chunk * 16);

  f32x4 acc[4][4];
#pragma unroll
  for (int m = 0; m < 4; ++m)
#pragma unroll
    for (int n = 0; n < 4; ++n) acc[m][n] = (f32x4)0.f;

#define STAGE_A(tt) do { unsigned so = (unsigned)(((tt) & 3) << 14);           \
    GLL(agp0 + (size_t)(tt) * 32, lds_raw + so + tid * 16);                    \
    GLL(agp1 + (size_t)(tt) * 32, lds_raw + so + 4096 + tid * 16); } while (0)
#define STAGE_B(tt) do { unsigned so = (unsigned)(((tt) & 3) << 14);           \
    GLL(bgp0 + (size_t)(tt) * 32, lds_raw + so + 8192 + tid * 16);             \
    GLL(bgp1 + (size_t)(tt) * 32, lds_raw + so + 12288 + tid * 16); } while (0)

  STAGE_A(0); STAGE_B(0); STAGE_A(1); STAGE_B(1); STAGE_A(2); STAGE_B(2);

  for (int t = 0; t < NT; ++t) {
    const int rem = NT - 1 - t;
    if (rem >= 2)      asm volatile("s_waitcnt vmcnt(8)" ::: "memory");
    else if (rem == 1) asm volatile("s_waitcnt vmcnt(4)" ::: "memory");
    else               asm volatile("s_waitcnt vmcnt(0)" ::: "memory");
    FENCE(); __builtin_amdgcn_s_barrier(); FENCE();
    __builtin_amdgcn_sched_barrier(0);

    if (t + 3 < NT) { STAGE_A(t + 3); STAGE_B(t + 3); }

    const unsigned sbase = ldsbase + (unsigned)((t & 3) << 14);
    u16x8 b[4], a[4];
    DSREAD(b[0], sbase + boff);
    DSREAD(b[1], sbase + boff + 1024);
    DSREAD(b[2], sbase + boff + 2048);
    DSREAD(b[3], sbase + boff + 3072);
    DSREAD(a[0], sbase + aoff);
    DSREAD(a[1], sbase + aoff + 1024);
    DSREAD(a[2], sbase + aoff + 2048);
    DSREAD(a[3], sbase + aoff + 3072);

    __builtin_amdgcn_s_setprio(1);
#define CLUSTER(m, g)                                                          \
    LGKM(g);                                                                   \
    acc[m][0] = __builtin_amdgcn_mfma_f32_16x16x32_bf16(                       \
        __builtin_bit_cast(bf16x8, a[m]), __builtin_bit_cast(bf16x8, b[0]),    \
        acc[m][0], 0, 0, 0);                                                   \
    acc[m][1] = __builtin_amdgcn_mfma_f32_16x16x32_bf16(                       \
        __builtin_bit_cast(bf16x8, a[m]), __builtin_bit_cast(bf16x8, b[1]),    \
        acc[m][1], 0, 0, 0);                                                   \
    acc[m][2] = __builtin_amdgcn_mfma_f32_16x16x32_bf16(                       \
        __builtin_bit_cast(bf16x8, a[m]), __builtin_bit_cast(bf16x8, b[2]),    \
        acc[m][2], 0, 0, 0);                                                   \
    acc[m][3] = __builtin_amdgcn_mfma_f32_16x16x32_bf16(                       \
        __builtin_bit_cast(bf16x8, a[m]), __builtin_bit_cast(bf16x8, b[3]),    \
        acc[m][3], 0, 0, 0)

    CLUSTER(0, 3);
    CLUSTER(1, 2);
    CLUSTER(2, 1);
    CLUSTER(3, 0);
#undef CLUSTER
    __builtin_amdgcn_s_setprio(0);
    __builtin_amdgcn_sched_barrier(0);
  }
#undef STAGE_A
#undef STAGE_B

  const int rowBase = bm * 128 + wr * 64 + lg * 4;
  const int colBase = bn * 128 + wc * 64 + lr;
#pragma unroll
  for (int n = 0; n < 4; ++n) {
    int col = colBase + n * 16;
#pragma unroll
    for (int m = 0; m < 4; ++m) {
      int row = rowBase + m * 16;
#pragma unroll
      for (int j = 0; j < 4; ++j)
        outB[(size_t)(row + j) * N + col] = f2bf(acc[m][n][j]);
    }
  }
}

// ---------------------------------------------------------------------------
// 256x256 bf16 MFMA GEMM, K32 slots, ring of 4 (128KB), 8 waves (2Mx4N).
// r5 schedule (counted vmcnt + counted lgkm clusters, T1/T2/T5).
// Three-way epilogue:
//   bn <  nFtiles : C+bias -> f32 outF (no relu), row stride NF
//   bn <  nHtiles : relu(C+bias) -> bf16 outB at col-(nFtiles*256), stride NB
//   bn >= nHtiles : FUSED HEAD — per-row sum relu(C+bias)*hvec[col],
//                   16-lane shfl reduce, atomicAdd into hout[row].
// ---------------------------------------------------------------------------
__global__ __launch_bounds__(512)
void gemm256_kernel(const unsigned short* __restrict__ A,
                    const unsigned short* __restrict__ BT,
                    const float* __restrict__ bias,
                    float* __restrict__ outF,
                    unsigned short* __restrict__ outB,
                    const float* __restrict__ hvec,
                    float* __restrict__ hout,
                    int lda, int K, int NF, int NB,
                    int nFtiles, int nHtiles, int gmx) {
  const int NT = K >> 5;                      // K32 tiles

  // T1: bijective XCD swizzle, bm fastest (r5-proven)
  const int nwg = gridDim.x;
  const int q = nwg >> 3, r = nwg & 7;
  const int xcd = blockIdx.x & 7, lid = blockIdx.x >> 3;
  const int wg2 = (xcd < r ? xcd * (q + 1) : r * (q + 1) + (xcd - r) * q) + lid;
  const int bm = wg2 % gmx, bn = wg2 / gmx;

  const int tid  = threadIdx.x;
  const int wid  = tid >> 6, lane = tid & 63;
  const int wr   = wid >> 2, wc = wid & 3;          // 2 x 4 waves
  const int lr   = lane & 15, lg = lane >> 4;

  // ---- staging (pre-swizzled global source, linear LDS dest) ----
  const int srow = tid >> 2;
  const int scol = ((tid & 3) ^ ((tid >> 3) & 3)) * 8;   // elems
  const unsigned short* agp0 = A  + (size_t)(bm * 256 + srow) * lda + scol;
  const unsigned short* agp1 = agp0 + (size_t)128 * lda;
  const unsigned short* bgp0 = BT + (size_t)(bn * 256 + srow) * K + scol;
  const unsigned short* bgp1 = bgp0 + (size_t)128 * K;

  // ---- read-side swizzled fragment offsets (0 bank conflicts) ----
  const int chunk = lg ^ ((lr >> 1) & 3);
  const unsigned ldsbase = (unsigned)(uintptr_t)&lds_raw[0];
  const unsigned aoff = (unsigned)((wr * 128 + lr) * 64 + chunk * 16);
  const unsigned boff = (unsigned)(16384 + (wc * 64 + lr) * 64 + chunk * 16);

  f32x4 acc[8][4];
#pragma unroll
  for (int m = 0; m < 8; ++m)
#pragma unroll
    for (int n = 0; n < 4; ++n) acc[m][n] = (f32x4)0.f;

#define STAGE_A(tt) do { unsigned so = (unsigned)(((tt) & 3) << 15);           \
    GLL(agp0 + (size_t)(tt) * 32, lds_raw + so + tid * 16);                    \
    GLL(agp1 + (size_t)(tt) * 32, lds_raw + so + 8192 + tid * 16); } while (0)
#define STAGE_B(tt) do { unsigned so = (unsigned)(((tt) & 3) << 15);           \
    GLL(bgp0 + (size_t)(tt) * 32, lds_raw + so + 16384 + tid * 16);            \
    GLL(bgp1 + (size_t)(tt) * 32, lds_raw + so + 24576 + tid * 16); } while (0)

  // prologue: tiles 0,1,2 staged (12 loads in flight)
  STAGE_A(0); STAGE_B(0); STAGE_A(1); STAGE_B(1); STAGE_A(2); STAGE_B(2);

  for (int t = 0; t < NT; ++t) {
    const int rem = NT - 1 - t;
    // gate slot t (oldest 4 loads) while keeping up to 8 in flight (T4)
    if (rem >= 2)      asm volatile("s_waitcnt vmcnt(8)" ::: "memory");
    else if (rem == 1) asm volatile("s_waitcnt vmcnt(4)" ::: "memory");
    else               asm volatile("s_waitcnt vmcnt(0)" ::: "memory");
    FENCE(); __builtin_amdgcn_s_barrier(); FENCE();
    __builtin_amdgcn_sched_barrier(0);

    // stage tile t+3 into slot (t-1)&3 (safe after this tile's barrier)
    if (t + 3 < NT) { STAGE_A(t + 3); STAGE_B(t + 3); }

    const unsigned sbase = ldsbase + (unsigned)((t & 3) << 15);

    // issue ALL reads in consumption order: b0-3 then a0-7
    u16x8 b[4], a[8];
    DSREAD(b[0], sbase + boff);
    DSREAD(b[1], sbase + boff + 1024);
    DSREAD(b[2], sbase + boff + 2048);
    DSREAD(b[3], sbase + boff + 3072);
    DSREAD(a[0], sbase + aoff);
    DSREAD(a[1], sbase + aoff + 1024);
    DSREAD(a[2], sbase + aoff + 2048);
    DSREAD(a[3], sbase + aoff + 3072);
    DSREAD(a[4], sbase + aoff + 4096);
    DSREAD(a[5], sbase + aoff + 5120);
    DSREAD(a[6], sbase + aoff + 6144);
    DSREAD(a[7], sbase + aoff + 7168);

    // 8 clusters: counted lgkm gate -> 4 MFMA; LDS serves ahead under MFMA
    __builtin_amdgcn_s_setprio(1);
#define CLUSTER(m, g)                                                          \
    LGKM(g);                                                                   \
    acc[m][0] = __builtin_amdgcn_mfma_f32_16x16x32_bf16(                       \
        __builtin_bit_cast(bf16x8, a[m]), __builtin_bit_cast(bf16x8, b[0]),    \
        acc[m][0], 0, 0, 0);                                                   \
    acc[m][1] = __builtin_amdgcn_mfma_f32_16x16x32_bf16(                       \
        __builtin_bit_cast(bf16x8, a[m]), __builtin_bit_cast(bf16x8, b[1]),    \
        acc[m][1], 0, 0, 0);                                                   \
    acc[m][2] = __builtin_amdgcn_mfma_f32_16x16x32_bf16(                       \
        __builtin_bit_cast(bf16x8, a[m]), __builtin_bit_cast(bf16x8, b[2]),    \
        acc[m][2], 0, 0, 0);                                                   \
    acc[m][3] = __builtin_amdgcn_mfma_f32_16x16x32_bf16(                       \
        __builtin_bit_cast(bf16x8, a[m]), __builtin_bit_cast(bf16x8, b[3]),    \
        acc[m][3], 0, 0, 0)

    CLUSTER(0, 7);
    CLUSTER(1, 6);
    CLUSTER(2, 5);
    CLUSTER(3, 4);
    CLUSTER(4, 3);
    CLUSTER(5, 2);
    CLUSTER(6, 1);
    CLUSTER(7, 0);
#undef CLUSTER
    __builtin_amdgcn_s_setprio(0);
    __builtin_amdgcn_sched_barrier(0);
  }
#undef STAGE_A
#undef STAGE_B

  const int rowBase = bm * 256 + wr * 128 + lg * 4;
  const int colBase = bn * 256 + wc * 64 + lr;
  if (bn < nFtiles) {
#pragma unroll
    for (int n = 0; n < 4; ++n) {
      int col = colBase + n * 16;
      float bv = bias[col];
#pragma unroll
      for (int m = 0; m < 8; ++m) {
        int row = rowBase + m * 16;
#pragma unroll
        for (int j = 0; j < 4; ++j)
          outF[(size_t)(row + j) * NF + col] = acc[m][n][j] + bv;
      }
    }
  } else if (bn < nHtiles) {
    const int colB = colBase - nFtiles * 256;
#pragma unroll
    for (int n = 0; n < 4; ++n) {
      int col = colB + n * 16;
      float bv = bias[colBase + n * 16];
#pragma unroll
      for (int m = 0; m < 8; ++m) {
        int row = rowBase + m * 16;
#pragma unroll
        for (int j = 0; j < 4; ++j)
          outB[(size_t)(row + j) * NB + col] = f2bf(fmaxf(acc[m][n][j] + bv, 0.f));
      }
    }
  } else {
    // fused head: hout[row] += sum_col relu(C+bias)*hvec[col]
    const int hcol0 = colBase - nHtiles * 256;
    float bv[4], hv[4];
#pragma unroll
    for (int n = 0; n < 4; ++n) {
      bv[n] = bias[colBase + n * 16];
      hv[n] = hvec[hcol0 + n * 16];
    }
#pragma unroll
    for (int m = 0; m < 8; ++m) {
#pragma unroll
      for (int j = 0; j < 4; ++j) {
        float s = 0.f;
#pragma unroll
        for (int n = 0; n < 4; ++n)
          s += fmaxf(acc[m][n][j] + bv[n], 0.f) * hv[n];
        s += __shfl_xor(s, 1);
        s += __shfl_xor(s, 2);
        s += __shfl_xor(s, 4);
        s += __shfl_xor(s, 8);
        if (lr == 0)
          atomicAdd(&hout[rowBase + m * 16 + j], s);
      }
    }
  }
}

// ---------------------------------------------------------------------------
extern "C" void kernel_launch(void* const* d_in, const int* in_sizes, int n_in,
                              void* d_out, int out_size, void* d_ws, size_t ws_size,
                              hipStream_t stream) {
  const float* x     = (const float*)d_in[0];
  const float* field = (const float*)d_in[1];
  const float* fw1   = (const float*)d_in[2];
  const float* fb1   = (const float*)d_in[3];
  const float* fw2   = (const float*)d_in[4];
  const float* fb2   = (const float*)d_in[5];
  const float* ww1   = (const float*)d_in[6];
  const float* wb1   = (const float*)d_in[7];
  const float* ww2   = (const float*)d_in[8];
  const float* wb2   = (const float*)d_in[9];
  const float* ww3   = (const float*)d_in[10];
  const float* wb3   = (const float*)d_in[11];
  const float* tw1   = (const float*)d_in[12];
  const float* tb1   = (const float*)d_in[13];
  const float* tw2   = (const float*)d_in[14];
  const float* tb2   = (const float*)d_in[15];

  const int M = 16384;
  float* outF    = (float*)d_out;                  // field_output [16384,4096]
  float* outWil  = outF + (size_t)M * 4096;
  float* outTop  = outWil + M;
  float* outPlaq = outTop + M;

  char* ws = (char*)d_ws;
  const size_t MB = 1048576;
  unsigned short* hbuf    = (unsigned short*)(ws);              // [16384,2048] 64MB
  unsigned short* catbuf  = (unsigned short*)(ws + 64  * MB);   // [16384,2048] 64MB (w1)
  unsigned short* catT    = (unsigned short*)(ws + 192 * MB);   // [4096,4096]  32MB
  unsigned short* fw2T    = (unsigned short*)(ws + 224 * MB);   // [4096,2048]  16MB  \ contiguous =
  unsigned short* W2catT  = (unsigned short*)(ws + 240 * MB);   // [4096,2048]  16MB  / BTcat [8192,2048]
  unsigned short* BTcat   = fw2T;
  unsigned short* fw2bf   = (unsigned short*)(ws + 256 * MB);   // [2048,4096]  16MB
  unsigned short* ww2T    = (unsigned short*)(ws + 272 * MB);   // [1024,2048]  4MB
  float*          biascat = (float*)(ws + 276 * MB);            // [8192] 32KB

  const int SMEM = 131072;   // 4-slot ring (gemm256)
  (void)hipFuncSetAttribute((const void*)gemm256_kernel,
                            hipFuncAttributeMaxDynamicSharedMemorySize, SMEM);
  const int SMEM128 = 65536; // 4-slot ring of 16KB (gemm128f) -> 2 blocks/CU
  (void)hipFuncSetAttribute((const void*)gemm128f_kernel,
                            hipFuncAttributeMaxDynamicSharedMemorySize, SMEM128);

  // merged prep: fc1 + 3 transposes + cast + init heads + plaquette
  hipLaunchKernelGGL(prep_kernel, dim3(47169), dim3(256), 0, stream,
                     x, field, fw1, fb1, fw2, ww1, tw1, ww2, wb3, tb2,
                     hbuf, fw2T, catT, ww2T, fw2bf, outWil, outTop, outPlaq);

  // biascat (reads catT -> separate launch)
  hipLaunchKernelGGL(biascat_kernel, dim3(2048), dim3(256), 0, stream,
                     catT, fb2, wb1, tb1, biascat);

  // W2catT[n][k] = sum_j catT[n][j] * fw2bf[k][j]   (M=4096, N=2048, K=4096)
  hipLaunchKernelGGL(gemm128f_kernel, dim3(512), dim3(256), SMEM128, stream,
                     catT, fw2bf, W2catT, 2048, 4096, 32);

  // fused: C = h @ [fw2 | W2cat] + biascat   (M=16384, N=8192, K=2048)
  //   bn<16: field_output f32; 16<=bn<24: w1 relu bf16 (NB=2048);
  //   bn>=24: topology head fused (tw2 dot + atomicAdd outTop)
  hipLaunchKernelGGL(gemm256_kernel, dim3(64 * 32), dim3(512), SMEM, stream,
                     hbuf, BTcat, biascat, outF, catbuf, tw2, outTop,
                     2048, 2048, 4096, 2048, 16, 24, 64);

  // wilson: w2 = relu(w1 @ ww2 + wb2); outWil += w2 @ ww3  (all head blocks)
  hipLaunchKernelGGL(gemm256_kernel, dim3(64 * 4), dim3(512), SMEM, stream,
                     catbuf, ww2T, wb2, (float*)nullptr, (unsigned short*)nullptr,
                     ww3, outWil,
                     2048, 2048, 0, 0, 0, 0, 64);

  (void)in_sizes; (void)n_in; (void)out_size; (void)ws_size;
}

// Round 16
// 794.680 us; speedup vs baseline: 1.3138x; 1.0883x over previous
//
#include <hip/hip_runtime.h>

#define L 10

using bf16x8 = __attribute__((ext_vector_type(8))) __bf16;
using u16x8  = __attribute__((ext_vector_type(8))) unsigned short;
using f32x4  = __attribute__((ext_vector_type(4))) float;

__device__ __forceinline__ unsigned short f2bf(float f) {
  unsigned int u = __float_as_uint(f);
  u += 0x7FFFu + ((u >> 16) & 1u);          // RNE
  return (unsigned short)(u >> 16);
}
__device__ __forceinline__ float bf2f(unsigned short h) {
  return __uint_as_float(((unsigned int)h) << 16);
}

// ---------------------------------------------------------------------------
// Merged prep kernel — one launch replaces 7 (r15-proven):
//   [0,16384)     fc1            [16384,24576) transpose fw2
//   [24576,32768) transpose ww1  [32768,40960) transpose tw1
//   [40960,43008) transpose ww2  [43008,47104) cast fw2->bf16
//   [47104,47168) init heads     47168 plaquette
// ---------------------------------------------------------------------------
__global__ void prep_kernel(const float* __restrict__ x,
                            const float* __restrict__ field,
                            const float* __restrict__ fw1,
                            const float* __restrict__ fb1,
                            const float* __restrict__ fw2,
                            const float* __restrict__ ww1,
                            const float* __restrict__ tw1,
                            const float* __restrict__ ww2,
                            const float* __restrict__ wb3,
                            const float* __restrict__ tb2,
                            unsigned short* __restrict__ hbuf,
                            unsigned short* __restrict__ fw2T,
                            unsigned short* __restrict__ catT,
                            unsigned short* __restrict__ ww2T,
                            unsigned short* __restrict__ fw2bf,
                            float* __restrict__ outWil,
                            float* __restrict__ outTop,
                            float* __restrict__ outPlaq) {
  __shared__ float tile[32][33];
  const int b   = blockIdx.x;
  const int tid = threadIdx.x;

  if (b < 16384) {                       // ---- fc1 ----
    const int N = 2048;
    int m  = b;
    int n0 = tid * 8;
    float4 xv = *(const float4*)(x + (size_t)m * 4);
    unsigned short o[8];
#pragma unroll
    for (int j = 0; j < 8; ++j) {
      int n = n0 + j;
      float s = fb1[n] + xv.x * fw1[n] + xv.y * fw1[N + n]
                       + xv.z * fw1[2*N + n] + xv.w * fw1[3*N + n];
      o[j] = f2bf(fmaxf(s, 0.f));
    }
    *(u16x8*)(hbuf + (size_t)m * N + n0) = *(const u16x8*)o;
    return;
  }

  const float* W = nullptr; unsigned short* WT = nullptr;
  int K = 0, N = 0, bx = 0, by = 0;
  if (b < 24576)      { int b2 = b - 16384; W = fw2; WT = fw2T; K = 2048; N = 4096; bx = b2 % 128; by = b2 / 128; }
  else if (b < 32768) { int b2 = b - 24576; W = ww1; WT = catT; K = 4096; N = 2048; bx = b2 % 64;  by = b2 / 64;  }
  else if (b < 40960) { int b2 = b - 32768; W = tw1; WT = catT + (size_t)2048 * 4096; K = 4096; N = 2048; bx = b2 % 64; by = b2 / 64; }
  else if (b < 43008) { int b2 = b - 40960; W = ww2; WT = ww2T; K = 2048; N = 1024; bx = b2 % 32;  by = b2 / 32;  }

  if (W) {                               // ---- transpose+convert ----
    int tx = tid & 31, ty = tid >> 5;    // 32 x 8
    int n0 = bx * 32, k0 = by * 32;
#pragma unroll
    for (int i = 0; i < 32; i += 8)
      tile[ty + i][tx] = W[(size_t)(k0 + ty + i) * N + n0 + tx];
    __syncthreads();
#pragma unroll
    for (int i = 0; i < 32; i += 8)
      WT[(size_t)(n0 + ty + i) * K + k0 + tx] = f2bf(tile[tx][ty + i]);
    return;
  }

  if (b < 47104) {                       // ---- cast fw2 -> bf16 ----
    size_t i = ((size_t)(b - 43008) * 256 + tid) * 8;
    unsigned short o[8];
#pragma unroll
    for (int j = 0; j < 8; ++j) o[j] = f2bf(fw2[i + j]);
    *(u16x8*)(fw2bf + i) = *(const u16x8*)o;
    return;
  }

  if (b < 47168) {                       // ---- init heads ----
    int i = (b - 47104) * 256 + tid;
    outWil[i] = wb3[0];
    outTop[i] = tb2[0];
    return;
  }

  // ---- plaquette (b == 47168) ----
  if (tid != 0) return;
  int c[4];
#pragma unroll
  for (int i = 0; i < 4; ++i) {
    int v = (int)x[i];
    v %= L; if (v < 0) v += L;
    c[i] = v;
  }
  float S = 0.f;
  for (int mu = 0; mu < 4; ++mu)
    for (int nu = mu + 1; nu < 4; ++nu) {
      int p[4] = {c[0], c[1], c[2], c[3]};
      float l1 = field[((p[0]*L + p[1])*L + p[2])*4 + mu];
      p[mu] = (p[mu] + 1) % L;
      float l2 = field[((p[0]*L + p[1])*L + p[2])*4 + nu];
      p[nu] = (p[nu] + 1) % L;
      float l3 = field[((p[0]*L + p[1])*L + p[2])*4 + mu];
      float l4 = field[((c[0]*L + c[1])*L + c[2])*4 + nu];
      S += l1 + l2 - l3 - l4;
    }
  outPlaq[0] = expf(S);
}

// ---------------------------------------------------------------------------
// biascat: out[0:4096] = fb2; out[4096+m] = (m<2048?wb1[m]:tb1[m-2048])
//                                + sum_j catT[m][j]*fb2[j]    (wave per row)
// ---------------------------------------------------------------------------
__global__ void biascat_kernel(const unsigned short* __restrict__ catT,
                               const float* __restrict__ fb2,
                               const float* __restrict__ wb1,
                               const float* __restrict__ tb1,
                               float* __restrict__ out) {
  int w    = blockIdx.x * 4 + (threadIdx.x >> 6);   // 0..8191
  int lane = threadIdx.x & 63;
  if (w < 4096) { if (lane == 0) out[w] = fb2[w]; return; }
  int m = w - 4096;
  const unsigned short* row = catT + (size_t)m * 4096;
  float s = 0.f;
  for (int k = lane * 8; k < 4096; k += 512) {
    u16x8 v = *(const u16x8*)(row + k);
#pragma unroll
    for (int j = 0; j < 8; ++j) s += bf2f(v[j]) * fb2[k + j];
  }
#pragma unroll
  for (int off = 32; off; off >>= 1) s += __shfl_down(s, off);
  if (lane == 0) out[w] = s + (m < 2048 ? wb1[m] : tb1[m - 2048]);
}

#define GLL(gp, lp)                                                            \
  __builtin_amdgcn_global_load_lds(                                            \
      (const __attribute__((address_space(1))) unsigned int*)(gp),             \
      (__attribute__((address_space(3))) unsigned int*)(lp), 16, 0, 0)

#define DSREAD(dst, addr)                                                      \
  asm volatile("ds_read_b128 %0, %1" : "=v"(dst) : "v"(addr))

#define LGKM(n)                                                                \
  do { asm volatile("s_waitcnt lgkmcnt(" #n ")" ::: "memory");                 \
       __builtin_amdgcn_sched_barrier(0); } while (0)

#define FENCE() asm volatile("" ::: "memory")

extern __shared__ char lds_raw[];

// ---------------------------------------------------------------------------
// 128x128 bf16 MFMA GEMM with r5 counted schedule, ring-4 16KB slots (64KB,
// 2 blocks/CU). Raw bf16 out (W2catT producer). 4 waves (2Mx2N).
// ---------------------------------------------------------------------------
__global__ __launch_bounds__(256)
void gemm128f_kernel(const unsigned short* __restrict__ A,
                     const unsigned short* __restrict__ BT,
                     unsigned short* __restrict__ outB,
                     int N, int K, int gmx) {
  const int NT = K >> 5;

  const int nwg = gridDim.x;
  const int q = nwg >> 3, r = nwg & 7;
  const int xcd = blockIdx.x & 7, lid = blockIdx.x >> 3;
  const int wg2 = (xcd < r ? xcd * (q + 1) : r * (q + 1) + (xcd - r) * q) + lid;
  const int bm = wg2 % gmx, bn = wg2 / gmx;

  const int tid  = threadIdx.x;
  const int wid  = tid >> 6, lane = tid & 63;
  const int wr   = wid >> 1, wc = wid & 1;
  const int lr   = lane & 15, lg = lane >> 4;

  const int srow = tid >> 2;
  const int scol = ((tid & 3) ^ ((tid >> 3) & 3)) * 8;
  const unsigned short* agp0 = A  + (size_t)(bm * 128 + srow) * K + scol;
  const unsigned short* agp1 = agp0 + (size_t)64 * K;
  const unsigned short* bgp0 = BT + (size_t)(bn * 128 + srow) * K + scol;
  const unsigned short* bgp1 = bgp0 + (size_t)64 * K;

  const int chunk = lg ^ ((lr >> 1) & 3);
  const unsigned ldsbase = (unsigned)(uintptr_t)&lds_raw[0];
  const unsigned aoff = (unsigned)((wr * 64 + lr) * 64 + chunk * 16);
  const unsigned boff = (unsigned)(8192 + (wc * 64 + lr) * 64 + chunk * 16);

  f32x4 acc[4][4];
#pragma unroll
  for (int m = 0; m < 4; ++m)
#pragma unroll
    for (int n = 0; n < 4; ++n) acc[m][n] = (f32x4)0.f;

#define STAGE_A(tt) do { unsigned so = (unsigned)(((tt) & 3) << 14);           \
    GLL(agp0 + (size_t)(tt) * 32, lds_raw + so + tid * 16);                    \
    GLL(agp1 + (size_t)(tt) * 32, lds_raw + so + 4096 + tid * 16); } while (0)
#define STAGE_B(tt) do { unsigned so = (unsigned)(((tt) & 3) << 14);           \
    GLL(bgp0 + (size_t)(tt) * 32, lds_raw + so + 8192 + tid * 16);             \
    GLL(bgp1 + (size_t)(tt) * 32, lds_raw + so + 12288 + tid * 16); } while (0)

  STAGE_A(0); STAGE_B(0); STAGE_A(1); STAGE_B(1); STAGE_A(2); STAGE_B(2);

  for (int t = 0; t < NT; ++t) {
    const int rem = NT - 1 - t;
    if (rem >= 2)      asm volatile("s_waitcnt vmcnt(8)" ::: "memory");
    else if (rem == 1) asm volatile("s_waitcnt vmcnt(4)" ::: "memory");
    else               asm volatile("s_waitcnt vmcnt(0)" ::: "memory");
    FENCE(); __builtin_amdgcn_s_barrier(); FENCE();
    __builtin_amdgcn_sched_barrier(0);

    if (t + 3 < NT) { STAGE_A(t + 3); STAGE_B(t + 3); }

    const unsigned sbase = ldsbase + (unsigned)((t & 3) << 14);
    u16x8 b[4], a[4];
    DSREAD(b[0], sbase + boff);
    DSREAD(b[1], sbase + boff + 1024);
    DSREAD(b[2], sbase + boff + 2048);
    DSREAD(b[3], sbase + boff + 3072);
    DSREAD(a[0], sbase + aoff);
    DSREAD(a[1], sbase + aoff + 1024);
    DSREAD(a[2], sbase + aoff + 2048);
    DSREAD(a[3], sbase + aoff + 3072);

    __builtin_amdgcn_s_setprio(1);
#define CLUSTER(m, g)                                                          \
    LGKM(g);                                                                   \
    acc[m][0] = __builtin_amdgcn_mfma_f32_16x16x32_bf16(                       \
        __builtin_bit_cast(bf16x8, a[m]), __builtin_bit_cast(bf16x8, b[0]),    \
        acc[m][0], 0, 0, 0);                                                   \
    acc[m][1] = __builtin_amdgcn_mfma_f32_16x16x32_bf16(                       \
        __builtin_bit_cast(bf16x8, a[m]), __builtin_bit_cast(bf16x8, b[1]),    \
        acc[m][1], 0, 0, 0);                                                   \
    acc[m][2] = __builtin_amdgcn_mfma_f32_16x16x32_bf16(                       \
        __builtin_bit_cast(bf16x8, a[m]), __builtin_bit_cast(bf16x8, b[2]),    \
        acc[m][2], 0, 0, 0);                                                   \
    acc[m][3] = __builtin_amdgcn_mfma_f32_16x16x32_bf16(                       \
        __builtin_bit_cast(bf16x8, a[m]), __builtin_bit_cast(bf16x8, b[3]),    \
        acc[m][3], 0, 0, 0)

    CLUSTER(0, 3);
    CLUSTER(1, 2);
    CLUSTER(2, 1);
    CLUSTER(3, 0);
#undef CLUSTER
    __builtin_amdgcn_s_setprio(0);
    __builtin_amdgcn_sched_barrier(0);
  }
#undef STAGE_A
#undef STAGE_B

  const int rowBase = bm * 128 + wr * 64 + lg * 4;
  const int colBase = bn * 128 + wc * 64 + lr;
#pragma unroll
  for (int n = 0; n < 4; ++n) {
    int col = colBase + n * 16;
#pragma unroll
    for (int m = 0; m < 4; ++m) {
      int row = rowBase + m * 16;
#pragma unroll
      for (int j = 0; j < 4; ++j)
        outB[(size_t)(row + j) * N + col] = f2bf(acc[m][n][j]);
    }
  }
}

// ---------------------------------------------------------------------------
// 256x256 bf16 MFMA GEMM, K32 slots, ring of 4 (128KB), 8 waves (2Mx4N).
// r5 schedule (counted vmcnt + counted lgkm clusters, T1/T2/T5).
// Three-way epilogue:
//   bn <  nFtiles : C+bias -> f32 outF via NON-TEMPORAL store (r10: -26us,
//                   output never re-read; keeps A/B L3-resident)
//   bn <  nHtiles : relu(C+bias) -> bf16 outB (cached: re-read by wilson)
//   bn >= nHtiles : FUSED HEAD — per-row sum relu(C+bias)*hvec[col],
//                   16-lane shfl reduce, atomicAdd into hout[row].
// ---------------------------------------------------------------------------
__global__ __launch_bounds__(512)
void gemm256_kernel(const unsigned short* __restrict__ A,
                    const unsigned short* __restrict__ BT,
                    const float* __restrict__ bias,
                    float* __restrict__ outF,
                    unsigned short* __restrict__ outB,
                    const float* __restrict__ hvec,
                    float* __restrict__ hout,
                    int lda, int K, int NF, int NB,
                    int nFtiles, int nHtiles, int gmx) {
  const int NT = K >> 5;                      // K32 tiles

  // T1: bijective XCD swizzle, bm fastest (r5-proven)
  const int nwg = gridDim.x;
  const int q = nwg >> 3, r = nwg & 7;
  const int xcd = blockIdx.x & 7, lid = blockIdx.x >> 3;
  const int wg2 = (xcd < r ? xcd * (q + 1) : r * (q + 1) + (xcd - r) * q) + lid;
  const int bm = wg2 % gmx, bn = wg2 / gmx;

  const int tid  = threadIdx.x;
  const int wid  = tid >> 6, lane = tid & 63;
  const int wr   = wid >> 2, wc = wid & 3;          // 2 x 4 waves
  const int lr   = lane & 15, lg = lane >> 4;

  // ---- staging (pre-swizzled global source, linear LDS dest) ----
  const int srow = tid >> 2;
  const int scol = ((tid & 3) ^ ((tid >> 3) & 3)) * 8;   // elems
  const unsigned short* agp0 = A  + (size_t)(bm * 256 + srow) * lda + scol;
  const unsigned short* agp1 = agp0 + (size_t)128 * lda;
  const unsigned short* bgp0 = BT + (size_t)(bn * 256 + srow) * K + scol;
  const unsigned short* bgp1 = bgp0 + (size_t)128 * K;

  // ---- read-side swizzled fragment offsets (0 bank conflicts) ----
  const int chunk = lg ^ ((lr >> 1) & 3);
  const unsigned ldsbase = (unsigned)(uintptr_t)&lds_raw[0];
  const unsigned aoff = (unsigned)((wr * 128 + lr) * 64 + chunk * 16);
  const unsigned boff = (unsigned)(16384 + (wc * 64 + lr) * 64 + chunk * 16);

  f32x4 acc[8][4];
#pragma unroll
  for (int m = 0; m < 8; ++m)
#pragma unroll
    for (int n = 0; n < 4; ++n) acc[m][n] = (f32x4)0.f;

#define STAGE_A(tt) do { unsigned so = (unsigned)(((tt) & 3) << 15);           \
    GLL(agp0 + (size_t)(tt) * 32, lds_raw + so + tid * 16);                    \
    GLL(agp1 + (size_t)(tt) * 32, lds_raw + so + 8192 + tid * 16); } while (0)
#define STAGE_B(tt) do { unsigned so = (unsigned)(((tt) & 3) << 15);           \
    GLL(bgp0 + (size_t)(tt) * 32, lds_raw + so + 16384 + tid * 16);            \
    GLL(bgp1 + (size_t)(tt) * 32, lds_raw + so + 24576 + tid * 16); } while (0)

  // prologue: tiles 0,1,2 staged (12 loads in flight)
  STAGE_A(0); STAGE_B(0); STAGE_A(1); STAGE_B(1); STAGE_A(2); STAGE_B(2);

  for (int t = 0; t < NT; ++t) {
    const int rem = NT - 1 - t;
    // gate slot t (oldest 4 loads) while keeping up to 8 in flight (T4)
    if (rem >= 2)      asm volatile("s_waitcnt vmcnt(8)" ::: "memory");
    else if (rem == 1) asm volatile("s_waitcnt vmcnt(4)" ::: "memory");
    else               asm volatile("s_waitcnt vmcnt(0)" ::: "memory");
    FENCE(); __builtin_amdgcn_s_barrier(); FENCE();
    __builtin_amdgcn_sched_barrier(0);

    // stage tile t+3 into slot (t-1)&3 (safe after this tile's barrier)
    if (t + 3 < NT) { STAGE_A(t + 3); STAGE_B(t + 3); }

    const unsigned sbase = ldsbase + (unsigned)((t & 3) << 15);

    // issue ALL reads in consumption order: b0-3 then a0-7
    u16x8 b[4], a[8];
    DSREAD(b[0], sbase + boff);
    DSREAD(b[1], sbase + boff + 1024);
    DSREAD(b[2], sbase + boff + 2048);
    DSREAD(b[3], sbase + boff + 3072);
    DSREAD(a[0], sbase + aoff);
    DSREAD(a[1], sbase + aoff + 1024);
    DSREAD(a[2], sbase + aoff + 2048);
    DSREAD(a[3], sbase + aoff + 3072);
    DSREAD(a[4], sbase + aoff + 4096);
    DSREAD(a[5], sbase + aoff + 5120);
    DSREAD(a[6], sbase + aoff + 6144);
    DSREAD(a[7], sbase + aoff + 7168);

    // 8 clusters: counted lgkm gate -> 4 MFMA; LDS serves ahead under MFMA
    __builtin_amdgcn_s_setprio(1);
#define CLUSTER(m, g)                                                          \
    LGKM(g);                                                                   \
    acc[m][0] = __builtin_amdgcn_mfma_f32_16x16x32_bf16(                       \
        __builtin_bit_cast(bf16x8, a[m]), __builtin_bit_cast(bf16x8, b[0]),    \
        acc[m][0], 0, 0, 0);                                                   \
    acc[m][1] = __builtin_amdgcn_mfma_f32_16x16x32_bf16(                       \
        __builtin_bit_cast(bf16x8, a[m]), __builtin_bit_cast(bf16x8, b[1]),    \
        acc[m][1], 0, 0, 0);                                                   \
    acc[m][2] = __builtin_amdgcn_mfma_f32_16x16x32_bf16(                       \
        __builtin_bit_cast(bf16x8, a[m]), __builtin_bit_cast(bf16x8, b[2]),    \
        acc[m][2], 0, 0, 0);                                                   \
    acc[m][3] = __builtin_amdgcn_mfma_f32_16x16x32_bf16(                       \
        __builtin_bit_cast(bf16x8, a[m]), __builtin_bit_cast(bf16x8, b[3]),    \
        acc[m][3], 0, 0, 0)

    CLUSTER(0, 7);
    CLUSTER(1, 6);
    CLUSTER(2, 5);
    CLUSTER(3, 4);
    CLUSTER(4, 3);
    CLUSTER(5, 2);
    CLUSTER(6, 1);
    CLUSTER(7, 0);
#undef CLUSTER
    __builtin_amdgcn_s_setprio(0);
    __builtin_amdgcn_sched_barrier(0);
  }
#undef STAGE_A
#undef STAGE_B

  const int rowBase = bm * 256 + wr * 128 + lg * 4;
  const int colBase = bn * 256 + wc * 64 + lr;
  if (bn < nFtiles) {
#pragma unroll
    for (int n = 0; n < 4; ++n) {
      int col = colBase + n * 16;
      float bv = bias[col];
#pragma unroll
      for (int m = 0; m < 8; ++m) {
        int row = rowBase + m * 16;
#pragma unroll
        for (int j = 0; j < 4; ++j)
          __builtin_nontemporal_store(acc[m][n][j] + bv,
                                      &outF[(size_t)(row + j) * NF + col]);
      }
    }
  } else if (bn < nHtiles) {
    const int colB = colBase - nFtiles * 256;
#pragma unroll
    for (int n = 0; n < 4; ++n) {
      int col = colB + n * 16;
      float bv = bias[colBase + n * 16];
#pragma unroll
      for (int m = 0; m < 8; ++m) {
        int row = rowBase + m * 16;
#pragma unroll
        for (int j = 0; j < 4; ++j)
          outB[(size_t)(row + j) * NB + col] = f2bf(fmaxf(acc[m][n][j] + bv, 0.f));
      }
    }
  } else {
    // fused head: hout[row] += sum_col relu(C+bias)*hvec[col]
    const int hcol0 = colBase - nHtiles * 256;
    float bv[4], hv[4];
#pragma unroll
    for (int n = 0; n < 4; ++n) {
      bv[n] = bias[colBase + n * 16];
      hv[n] = hvec[hcol0 + n * 16];
    }
#pragma unroll
    for (int m = 0; m < 8; ++m) {
#pragma unroll
      for (int j = 0; j < 4; ++j) {
        float s = 0.f;
#pragma unroll
        for (int n = 0; n < 4; ++n)
          s += fmaxf(acc[m][n][j] + bv[n], 0.f) * hv[n];
        s += __shfl_xor(s, 1);
        s += __shfl_xor(s, 2);
        s += __shfl_xor(s, 4);
        s += __shfl_xor(s, 8);
        if (lr == 0)
          atomicAdd(&hout[rowBase + m * 16 + j], s);
      }
    }
  }
}

// ---------------------------------------------------------------------------
extern "C" void kernel_launch(void* const* d_in, const int* in_sizes, int n_in,
                              void* d_out, int out_size, void* d_ws, size_t ws_size,
                              hipStream_t stream) {
  const float* x     = (const float*)d_in[0];
  const float* field = (const float*)d_in[1];
  const float* fw1   = (const float*)d_in[2];
  const float* fb1   = (const float*)d_in[3];
  const float* fw2   = (const float*)d_in[4];
  const float* fb2   = (const float*)d_in[5];
  const float* ww1   = (const float*)d_in[6];
  const float* wb1   = (const float*)d_in[7];
  const float* ww2   = (const float*)d_in[8];
  const float* wb2   = (const float*)d_in[9];
  const float* ww3   = (const float*)d_in[10];
  const float* wb3   = (const float*)d_in[11];
  const float* tw1   = (const float*)d_in[12];
  const float* tb1   = (const float*)d_in[13];
  const float* tw2   = (const float*)d_in[14];
  const float* tb2   = (const float*)d_in[15];

  const int M = 16384;
  float* outF    = (float*)d_out;                  // field_output [16384,4096]
  float* outWil  = outF + (size_t)M * 4096;
  float* outTop  = outWil + M;
  float* outPlaq = outTop + M;

  char* ws = (char*)d_ws;
  const size_t MB = 1048576;
  unsigned short* hbuf    = (unsigned short*)(ws);              // [16384,2048] 64MB
  unsigned short* catbuf  = (unsigned short*)(ws + 64  * MB);   // [16384,2048] 64MB (w1)
  unsigned short* catT    = (unsigned short*)(ws + 192 * MB);   // [4096,4096]  32MB
  unsigned short* fw2T    = (unsigned short*)(ws + 224 * MB);   // [4096,2048]  16MB  \ contiguous =
  unsigned short* W2catT  = (unsigned short*)(ws + 240 * MB);   // [4096,2048]  16MB  / BTcat [8192,2048]
  unsigned short* BTcat   = fw2T;
  unsigned short* fw2bf   = (unsigned short*)(ws + 256 * MB);   // [2048,4096]  16MB
  unsigned short* ww2T    = (unsigned short*)(ws + 272 * MB);   // [1024,2048]  4MB
  float*          biascat = (float*)(ws + 276 * MB);            // [8192] 32KB

  const int SMEM = 131072;   // 4-slot ring (gemm256)
  (void)hipFuncSetAttribute((const void*)gemm256_kernel,
                            hipFuncAttributeMaxDynamicSharedMemorySize, SMEM);
  const int SMEM128 = 65536; // 4-slot ring of 16KB (gemm128f) -> 2 blocks/CU
  (void)hipFuncSetAttribute((const void*)gemm128f_kernel,
                            hipFuncAttributeMaxDynamicSharedMemorySize, SMEM128);

  // merged prep: fc1 + 3 transposes + cast + init heads + plaquette
  hipLaunchKernelGGL(prep_kernel, dim3(47169), dim3(256), 0, stream,
                     x, field, fw1, fb1, fw2, ww1, tw1, ww2, wb3, tb2,
                     hbuf, fw2T, catT, ww2T, fw2bf, outWil, outTop, outPlaq);

  // biascat (reads catT -> separate launch)
  hipLaunchKernelGGL(biascat_kernel, dim3(2048), dim3(256), 0, stream,
                     catT, fb2, wb1, tb1, biascat);

  // W2catT[n][k] = sum_j catT[n][j] * fw2bf[k][j]   (M=4096, N=2048, K=4096)
  hipLaunchKernelGGL(gemm128f_kernel, dim3(512), dim3(256), SMEM128, stream,
                     catT, fw2bf, W2catT, 2048, 4096, 32);

  // fused: C = h @ [fw2 | W2cat] + biascat   (M=16384, N=8192, K=2048)
  //   bn<16: field_output f32 (NT stores); 16<=bn<24: w1 relu bf16 (NB=2048);
  //   bn>=24: topology head fused (tw2 dot + atomicAdd outTop)
  hipLaunchKernelGGL(gemm256_kernel, dim3(64 * 32), dim3(512), SMEM, stream,
                     hbuf, BTcat, biascat, outF, catbuf, tw2, outTop,
                     2048, 2048, 4096, 2048, 16, 24, 64);

  // wilson: w2 = relu(w1 @ ww2 + wb2); outWil += w2 @ ww3  (all head blocks)
  hipLaunchKernelGGL(gemm256_kernel, dim3(64 * 4), dim3(512), SMEM, stream,
                     catbuf, ww2T, wb2, (float*)nullptr, (unsigned short*)nullptr,
                     ww3, outWil,
                     2048, 2048, 0, 0, 0, 0, 64);

  (void)in_sizes; (void)n_in; (void)out_size; (void)ws_size;
}

// Round 17
// 791.287 us; speedup vs baseline: 1.3194x; 1.0043x over previous
//
#include <hip/hip_runtime.h>

#define L 10

using bf16x8 = __attribute__((ext_vector_type(8))) __bf16;
using u16x8  = __attribute__((ext_vector_type(8))) unsigned short;
using f32x4  = __attribute__((ext_vector_type(4))) float;

__device__ __forceinline__ unsigned short f2bf(float f) {
  unsigned int u = __float_as_uint(f);
  u += 0x7FFFu + ((u >> 16) & 1u);          // RNE
  return (unsigned short)(u >> 16);
}
__device__ __forceinline__ float bf2f(unsigned short h) {
  return __uint_as_float(((unsigned int)h) << 16);
}

// ---------------------------------------------------------------------------
// Merged prep kernel — one launch replaces 7 (r15-proven):
//   [0,16384)     fc1            [16384,24576) transpose fw2
//   [24576,32768) transpose ww1  [32768,40960) transpose tw1
//   [40960,43008) transpose ww2  [43008,47104) cast fw2->bf16
//   [47104,47168) init heads     47168 plaquette
// ---------------------------------------------------------------------------
__global__ void prep_kernel(const float* __restrict__ x,
                            const float* __restrict__ field,
                            const float* __restrict__ fw1,
                            const float* __restrict__ fb1,
                            const float* __restrict__ fw2,
                            const float* __restrict__ ww1,
                            const float* __restrict__ tw1,
                            const float* __restrict__ ww2,
                            const float* __restrict__ wb3,
                            const float* __restrict__ tb2,
                            unsigned short* __restrict__ hbuf,
                            unsigned short* __restrict__ fw2T,
                            unsigned short* __restrict__ catT,
                            unsigned short* __restrict__ ww2T,
                            unsigned short* __restrict__ fw2bf,
                            float* __restrict__ outWil,
                            float* __restrict__ outTop,
                            float* __restrict__ outPlaq) {
  __shared__ float tile[32][33];
  const int b   = blockIdx.x;
  const int tid = threadIdx.x;

  if (b < 16384) {                       // ---- fc1 ----
    const int N = 2048;
    int m  = b;
    int n0 = tid * 8;
    float4 xv = *(const float4*)(x + (size_t)m * 4);
    unsigned short o[8];
#pragma unroll
    for (int j = 0; j < 8; ++j) {
      int n = n0 + j;
      float s = fb1[n] + xv.x * fw1[n] + xv.y * fw1[N + n]
                       + xv.z * fw1[2*N + n] + xv.w * fw1[3*N + n];
      o[j] = f2bf(fmaxf(s, 0.f));
    }
    *(u16x8*)(hbuf + (size_t)m * N + n0) = *(const u16x8*)o;
    return;
  }

  const float* W = nullptr; unsigned short* WT = nullptr;
  int K = 0, N = 0, bx = 0, by = 0;
  if (b < 24576)      { int b2 = b - 16384; W = fw2; WT = fw2T; K = 2048; N = 4096; bx = b2 % 128; by = b2 / 128; }
  else if (b < 32768) { int b2 = b - 24576; W = ww1; WT = catT; K = 4096; N = 2048; bx = b2 % 64;  by = b2 / 64;  }
  else if (b < 40960) { int b2 = b - 32768; W = tw1; WT = catT + (size_t)2048 * 4096; K = 4096; N = 2048; bx = b2 % 64; by = b2 / 64; }
  else if (b < 43008) { int b2 = b - 40960; W = ww2; WT = ww2T; K = 2048; N = 1024; bx = b2 % 32;  by = b2 / 32;  }

  if (W) {                               // ---- transpose+convert ----
    int tx = tid & 31, ty = tid >> 5;    // 32 x 8
    int n0 = bx * 32, k0 = by * 32;
#pragma unroll
    for (int i = 0; i < 32; i += 8)
      tile[ty + i][tx] = W[(size_t)(k0 + ty + i) * N + n0 + tx];
    __syncthreads();
#pragma unroll
    for (int i = 0; i < 32; i += 8)
      WT[(size_t)(n0 + ty + i) * K + k0 + tx] = f2bf(tile[tx][ty + i]);
    return;
  }

  if (b < 47104) {                       // ---- cast fw2 -> bf16 ----
    size_t i = ((size_t)(b - 43008) * 256 + tid) * 8;
    unsigned short o[8];
#pragma unroll
    for (int j = 0; j < 8; ++j) o[j] = f2bf(fw2[i + j]);
    *(u16x8*)(fw2bf + i) = *(const u16x8*)o;
    return;
  }

  if (b < 47168) {                       // ---- init heads ----
    int i = (b - 47104) * 256 + tid;
    outWil[i] = wb3[0];
    outTop[i] = tb2[0];
    return;
  }

  // ---- plaquette (b == 47168) ----
  if (tid != 0) return;
  int c[4];
#pragma unroll
  for (int i = 0; i < 4; ++i) {
    int v = (int)x[i];
    v %= L; if (v < 0) v += L;
    c[i] = v;
  }
  float S = 0.f;
  for (int mu = 0; mu < 4; ++mu)
    for (int nu = mu + 1; nu < 4; ++nu) {
      int p[4] = {c[0], c[1], c[2], c[3]};
      float l1 = field[((p[0]*L + p[1])*L + p[2])*4 + mu];
      p[mu] = (p[mu] + 1) % L;
      float l2 = field[((p[0]*L + p[1])*L + p[2])*4 + nu];
      p[nu] = (p[nu] + 1) % L;
      float l3 = field[((p[0]*L + p[1])*L + p[2])*4 + mu];
      float l4 = field[((c[0]*L + c[1])*L + c[2])*4 + nu];
      S += l1 + l2 - l3 - l4;
    }
  outPlaq[0] = expf(S);
}

#define GLL(gp, lp)                                                            \
  __builtin_amdgcn_global_load_lds(                                            \
      (const __attribute__((address_space(1))) unsigned int*)(gp),             \
      (__attribute__((address_space(3))) unsigned int*)(lp), 16, 0, 0)

#define DSREAD(dst, addr)                                                      \
  asm volatile("ds_read_b128 %0, %1" : "=v"(dst) : "v"(addr))

#define LGKM(n)                                                                \
  do { asm volatile("s_waitcnt lgkmcnt(" #n ")" ::: "memory");                 \
       __builtin_amdgcn_sched_barrier(0); } while (0)

#define FENCE() asm volatile("" ::: "memory")

extern __shared__ char lds_raw[];

// ---------------------------------------------------------------------------
// Merged: blocks [0,512) = 128x128 bf16 MFMA GEMM (W2catT producer, r5
// counted schedule, ring-4 16KB slots, 64KB dyn LDS); blocks [512,2560) =
// biascat (independent of the GEMM; hides under it). Both consume only
// prep outputs; both outputs feed the big GEMM launched after.
// ---------------------------------------------------------------------------
__global__ __launch_bounds__(256)
void gemm128b_kernel(const unsigned short* __restrict__ A,
                     const unsigned short* __restrict__ BT,
                     unsigned short* __restrict__ outB,
                     int N, int K, int gmx,
                     const unsigned short* __restrict__ catT,
                     const float* __restrict__ fb2,
                     const float* __restrict__ wb1,
                     const float* __restrict__ tb1,
                     float* __restrict__ biasout) {
  if (blockIdx.x >= 512) {
    // ---- biascat role: out[0:4096]=fb2; out[4096+m]=bias_m + catT[m].fb2 --
    int w    = (blockIdx.x - 512) * 4 + (threadIdx.x >> 6);   // 0..8191
    int lane = threadIdx.x & 63;
    if (w < 4096) { if (lane == 0) biasout[w] = fb2[w]; return; }
    int m = w - 4096;
    const unsigned short* row = catT + (size_t)m * 4096;
    float s = 0.f;
    for (int k = lane * 8; k < 4096; k += 512) {
      u16x8 v = *(const u16x8*)(row + k);
#pragma unroll
      for (int j = 0; j < 8; ++j) s += bf2f(v[j]) * fb2[k + j];
    }
#pragma unroll
    for (int off = 32; off; off >>= 1) s += __shfl_down(s, off);
    if (lane == 0) biasout[w] = s + (m < 2048 ? wb1[m] : tb1[m - 2048]);
    return;
  }

  // ---- GEMM role (nwg pinned to 512 for the T1 swizzle) ----
  const int NT = K >> 5;
  const int nwg = 512;
  const int q = nwg >> 3;
  const int xcd = blockIdx.x & 7, lid = blockIdx.x >> 3;
  const int wg2 = xcd * q + lid;
  const int bm = wg2 % gmx, bn = wg2 / gmx;

  const int tid  = threadIdx.x;
  const int wid  = tid >> 6, lane = tid & 63;
  const int wr   = wid >> 1, wc = wid & 1;
  const int lr   = lane & 15, lg = lane >> 4;

  const int srow = tid >> 2;
  const int scol = ((tid & 3) ^ ((tid >> 3) & 3)) * 8;
  const unsigned short* agp0 = A  + (size_t)(bm * 128 + srow) * K + scol;
  const unsigned short* agp1 = agp0 + (size_t)64 * K;
  const unsigned short* bgp0 = BT + (size_t)(bn * 128 + srow) * K + scol;
  const unsigned short* bgp1 = bgp0 + (size_t)64 * K;

  const int chunk = lg ^ ((lr >> 1) & 3);
  const unsigned ldsbase = (unsigned)(uintptr_t)&lds_raw[0];
  const unsigned aoff = (unsigned)((wr * 64 + lr) * 64 + chunk * 16);
  const unsigned boff = (unsigned)(8192 + (wc * 64 + lr) * 64 + chunk * 16);

  f32x4 acc[4][4];
#pragma unroll
  for (int m = 0; m < 4; ++m)
#pragma unroll
    for (int n = 0; n < 4; ++n) acc[m][n] = (f32x4)0.f;

#define STAGE_A(tt) do { unsigned so = (unsigned)(((tt) & 3) << 14);           \
    GLL(agp0 + (size_t)(tt) * 32, lds_raw + so + tid * 16);                    \
    GLL(agp1 + (size_t)(tt) * 32, lds_raw + so + 4096 + tid * 16); } while (0)
#define STAGE_B(tt) do { unsigned so = (unsigned)(((tt) & 3) << 14);           \
    GLL(bgp0 + (size_t)(tt) * 32, lds_raw + so + 8192 + tid * 16);             \
    GLL(bgp1 + (size_t)(tt) * 32, lds_raw + so + 12288 + tid * 16); } while (0)

  STAGE_A(0); STAGE_B(0); STAGE_A(1); STAGE_B(1); STAGE_A(2); STAGE_B(2);

  for (int t = 0; t < NT; ++t) {
    const int rem = NT - 1 - t;
    if (rem >= 2)      asm volatile("s_waitcnt vmcnt(8)" ::: "memory");
    else if (rem == 1) asm volatile("s_waitcnt vmcnt(4)" ::: "memory");
    else               asm volatile("s_waitcnt vmcnt(0)" ::: "memory");
    FENCE(); __builtin_amdgcn_s_barrier(); FENCE();
    __builtin_amdgcn_sched_barrier(0);

    if (t + 3 < NT) { STAGE_A(t + 3); STAGE_B(t + 3); }

    const unsigned sbase = ldsbase + (unsigned)((t & 3) << 14);
    u16x8 b[4], a[4];
    DSREAD(b[0], sbase + boff);
    DSREAD(b[1], sbase + boff + 1024);
    DSREAD(b[2], sbase + boff + 2048);
    DSREAD(b[3], sbase + boff + 3072);
    DSREAD(a[0], sbase + aoff);
    DSREAD(a[1], sbase + aoff + 1024);
    DSREAD(a[2], sbase + aoff + 2048);
    DSREAD(a[3], sbase + aoff + 3072);

    __builtin_amdgcn_s_setprio(1);
#define CLUSTER(m, g)                                                          \
    LGKM(g);                                                                   \
    acc[m][0] = __builtin_amdgcn_mfma_f32_16x16x32_bf16(                       \
        __builtin_bit_cast(bf16x8, a[m]), __builtin_bit_cast(bf16x8, b[0]),    \
        acc[m][0], 0, 0, 0);                                                   \
    acc[m][1] = __builtin_amdgcn_mfma_f32_16x16x32_bf16(                       \
        __builtin_bit_cast(bf16x8, a[m]), __builtin_bit_cast(bf16x8, b[1]),    \
        acc[m][1], 0, 0, 0);                                                   \
    acc[m][2] = __builtin_amdgcn_mfma_f32_16x16x32_bf16(                       \
        __builtin_bit_cast(bf16x8, a[m]), __builtin_bit_cast(bf16x8, b[2]),    \
        acc[m][2], 0, 0, 0);                                                   \
    acc[m][3] = __builtin_amdgcn_mfma_f32_16x16x32_bf16(                       \
        __builtin_bit_cast(bf16x8, a[m]), __builtin_bit_cast(bf16x8, b[3]),    \
        acc[m][3], 0, 0, 0)

    CLUSTER(0, 3);
    CLUSTER(1, 2);
    CLUSTER(2, 1);
    CLUSTER(3, 0);
#undef CLUSTER
    __builtin_amdgcn_s_setprio(0);
    __builtin_amdgcn_sched_barrier(0);
  }
#undef STAGE_A
#undef STAGE_B

  const int rowBase = bm * 128 + wr * 64 + lg * 4;
  const int colBase = bn * 128 + wc * 64 + lr;
#pragma unroll
  for (int n = 0; n < 4; ++n) {
    int col = colBase + n * 16;
#pragma unroll
    for (int m = 0; m < 4; ++m) {
      int row = rowBase + m * 16;
#pragma unroll
      for (int j = 0; j < 4; ++j)
        outB[(size_t)(row + j) * N + col] = f2bf(acc[m][n][j]);
    }
  }
}

// ---------------------------------------------------------------------------
// 256x256 bf16 MFMA GEMM, K32 slots, ring of 4 (128KB), 8 waves (2Mx4N).
// r5 schedule (counted vmcnt + counted lgkm clusters, T1/T2/T5).
// Three-way epilogue:
//   bn <  nFtiles : C+bias -> f32 outF via NON-TEMPORAL store
//   bn <  nHtiles : relu(C+bias) -> bf16 outB (cached: re-read by wilson)
//   bn >= nHtiles : FUSED HEAD — per-row sum relu(C+bias)*hvec[col],
//                   16-lane shfl reduce, atomicAdd into hout[row].
// ---------------------------------------------------------------------------
__global__ __launch_bounds__(512)
void gemm256_kernel(const unsigned short* __restrict__ A,
                    const unsigned short* __restrict__ BT,
                    const float* __restrict__ bias,
                    float* __restrict__ outF,
                    unsigned short* __restrict__ outB,
                    const float* __restrict__ hvec,
                    float* __restrict__ hout,
                    int lda, int K, int NF, int NB,
                    int nFtiles, int nHtiles, int gmx) {
  const int NT = K >> 5;                      // K32 tiles

  // T1: bijective XCD swizzle, bm fastest (r5-proven)
  const int nwg = gridDim.x;
  const int q = nwg >> 3, r = nwg & 7;
  const int xcd = blockIdx.x & 7, lid = blockIdx.x >> 3;
  const int wg2 = (xcd < r ? xcd * (q + 1) : r * (q + 1) + (xcd - r) * q) + lid;
  const int bm = wg2 % gmx, bn = wg2 / gmx;

  const int tid  = threadIdx.x;
  const int wid  = tid >> 6, lane = tid & 63;
  const int wr   = wid >> 2, wc = wid & 3;          // 2 x 4 waves
  const int lr   = lane & 15, lg = lane >> 4;

  // ---- staging (pre-swizzled global source, linear LDS dest) ----
  const int srow = tid >> 2;
  const int scol = ((tid & 3) ^ ((tid >> 3) & 3)) * 8;   // elems
  const unsigned short* agp0 = A  + (size_t)(bm * 256 + srow) * lda + scol;
  const unsigned short* agp1 = agp0 + (size_t)128 * lda;
  const unsigned short* bgp0 = BT + (size_t)(bn * 256 + srow) * K + scol;
  const unsigned short* bgp1 = bgp0 + (size_t)128 * K;

  // ---- read-side swizzled fragment offsets (0 bank conflicts) ----
  const int chunk = lg ^ ((lr >> 1) & 3);
  const unsigned ldsbase = (unsigned)(uintptr_t)&lds_raw[0];
  const unsigned aoff = (unsigned)((wr * 128 + lr) * 64 + chunk * 16);
  const unsigned boff = (unsigned)(16384 + (wc * 64 + lr) * 64 + chunk * 16);

  f32x4 acc[8][4];
#pragma unroll
  for (int m = 0; m < 8; ++m)
#pragma unroll
    for (int n = 0; n < 4; ++n) acc[m][n] = (f32x4)0.f;

#define STAGE_A(tt) do { unsigned so = (unsigned)(((tt) & 3) << 15);           \
    GLL(agp0 + (size_t)(tt) * 32, lds_raw + so + tid * 16);                    \
    GLL(agp1 + (size_t)(tt) * 32, lds_raw + so + 8192 + tid * 16); } while (0)
#define STAGE_B(tt) do { unsigned so = (unsigned)(((tt) & 3) << 15);           \
    GLL(bgp0 + (size_t)(tt) * 32, lds_raw + so + 16384 + tid * 16);            \
    GLL(bgp1 + (size_t)(tt) * 32, lds_raw + so + 24576 + tid * 16); } while (0)

  // prologue: tiles 0,1,2 staged (12 loads in flight)
  STAGE_A(0); STAGE_B(0); STAGE_A(1); STAGE_B(1); STAGE_A(2); STAGE_B(2);

  for (int t = 0; t < NT; ++t) {
    const int rem = NT - 1 - t;
    // gate slot t (oldest 4 loads) while keeping up to 8 in flight (T4)
    if (rem >= 2)      asm volatile("s_waitcnt vmcnt(8)" ::: "memory");
    else if (rem == 1) asm volatile("s_waitcnt vmcnt(4)" ::: "memory");
    else               asm volatile("s_waitcnt vmcnt(0)" ::: "memory");
    FENCE(); __builtin_amdgcn_s_barrier(); FENCE();
    __builtin_amdgcn_sched_barrier(0);

    // stage tile t+3 into slot (t-1)&3 (safe after this tile's barrier)
    if (t + 3 < NT) { STAGE_A(t + 3); STAGE_B(t + 3); }

    const unsigned sbase = ldsbase + (unsigned)((t & 3) << 15);

    // issue ALL reads in consumption order: b0-3 then a0-7
    u16x8 b[4], a[8];
    DSREAD(b[0], sbase + boff);
    DSREAD(b[1], sbase + boff + 1024);
    DSREAD(b[2], sbase + boff + 2048);
    DSREAD(b[3], sbase + boff + 3072);
    DSREAD(a[0], sbase + aoff);
    DSREAD(a[1], sbase + aoff + 1024);
    DSREAD(a[2], sbase + aoff + 2048);
    DSREAD(a[3], sbase + aoff + 3072);
    DSREAD(a[4], sbase + aoff + 4096);
    DSREAD(a[5], sbase + aoff + 5120);
    DSREAD(a[6], sbase + aoff + 6144);
    DSREAD(a[7], sbase + aoff + 7168);

    // 8 clusters: counted lgkm gate -> 4 MFMA; LDS serves ahead under MFMA
    __builtin_amdgcn_s_setprio(1);
#define CLUSTER(m, g)                                                          \
    LGKM(g);                                                                   \
    acc[m][0] = __builtin_amdgcn_mfma_f32_16x16x32_bf16(                       \
        __builtin_bit_cast(bf16x8, a[m]), __builtin_bit_cast(bf16x8, b[0]),    \
        acc[m][0], 0, 0, 0);                                                   \
    acc[m][1] = __builtin_amdgcn_mfma_f32_16x16x32_bf16(                       \
        __builtin_bit_cast(bf16x8, a[m]), __builtin_bit_cast(bf16x8, b[1]),    \
        acc[m][1], 0, 0, 0);                                                   \
    acc[m][2] = __builtin_amdgcn_mfma_f32_16x16x32_bf16(                       \
        __builtin_bit_cast(bf16x8, a[m]), __builtin_bit_cast(bf16x8, b[2]),    \
        acc[m][2], 0, 0, 0);                                                   \
    acc[m][3] = __builtin_amdgcn_mfma_f32_16x16x32_bf16(                       \
        __builtin_bit_cast(bf16x8, a[m]), __builtin_bit_cast(bf16x8, b[3]),    \
        acc[m][3], 0, 0, 0)

    CLUSTER(0, 7);
    CLUSTER(1, 6);
    CLUSTER(2, 5);
    CLUSTER(3, 4);
    CLUSTER(4, 3);
    CLUSTER(5, 2);
    CLUSTER(6, 1);
    CLUSTER(7, 0);
#undef CLUSTER
    __builtin_amdgcn_s_setprio(0);
    __builtin_amdgcn_sched_barrier(0);
  }
#undef STAGE_A
#undef STAGE_B

  const int rowBase = bm * 256 + wr * 128 + lg * 4;
  const int colBase = bn * 256 + wc * 64 + lr;
  if (bn < nFtiles) {
#pragma unroll
    for (int n = 0; n < 4; ++n) {
      int col = colBase + n * 16;
      float bv = bias[col];
#pragma unroll
      for (int m = 0; m < 8; ++m) {
        int row = rowBase + m * 16;
#pragma unroll
        for (int j = 0; j < 4; ++j)
          __builtin_nontemporal_store(acc[m][n][j] + bv,
                                      &outF[(size_t)(row + j) * NF + col]);
      }
    }
  } else if (bn < nHtiles) {
    const int colB = colBase - nFtiles * 256;
#pragma unroll
    for (int n = 0; n < 4; ++n) {
      int col = colB + n * 16;
      float bv = bias[colBase + n * 16];
#pragma unroll
      for (int m = 0; m < 8; ++m) {
        int row = rowBase + m * 16;
#pragma unroll
        for (int j = 0; j < 4; ++j)
          outB[(size_t)(row + j) * NB + col] = f2bf(fmaxf(acc[m][n][j] + bv, 0.f));
      }
    }
  } else {
    // fused head: hout[row] += sum_col relu(C+bias)*hvec[col]
    const int hcol0 = colBase - nHtiles * 256;
    float bv[4], hv[4];
#pragma unroll
    for (int n = 0; n < 4; ++n) {
      bv[n] = bias[colBase + n * 16];
      hv[n] = hvec[hcol0 + n * 16];
    }
#pragma unroll
    for (int m = 0; m < 8; ++m) {
#pragma unroll
      for (int j = 0; j < 4; ++j) {
        float s = 0.f;
#pragma unroll
        for (int n = 0; n < 4; ++n)
          s += fmaxf(acc[m][n][j] + bv[n], 0.f) * hv[n];
        s += __shfl_xor(s, 1);
        s += __shfl_xor(s, 2);
        s += __shfl_xor(s, 4);
        s += __shfl_xor(s, 8);
        if (lr == 0)
          atomicAdd(&hout[rowBase + m * 16 + j], s);
      }
    }
  }
}

// ---------------------------------------------------------------------------
extern "C" void kernel_launch(void* const* d_in, const int* in_sizes, int n_in,
                              void* d_out, int out_size, void* d_ws, size_t ws_size,
                              hipStream_t stream) {
  const float* x     = (const float*)d_in[0];
  const float* field = (const float*)d_in[1];
  const float* fw1   = (const float*)d_in[2];
  const float* fb1   = (const float*)d_in[3];
  const float* fw2   = (const float*)d_in[4];
  const float* fb2   = (const float*)d_in[5];
  const float* ww1   = (const float*)d_in[6];
  const float* wb1   = (const float*)d_in[7];
  const float* ww2   = (const float*)d_in[8];
  const float* wb2   = (const float*)d_in[9];
  const float* ww3   = (const float*)d_in[10];
  const float* wb3   = (const float*)d_in[11];
  const float* tw1   = (const float*)d_in[12];
  const float* tb1   = (const float*)d_in[13];
  const float* tw2   = (const float*)d_in[14];
  const float* tb2   = (const float*)d_in[15];

  const int M = 16384;
  float* outF    = (float*)d_out;                  // field_output [16384,4096]
  float* outWil  = outF + (size_t)M * 4096;
  float* outTop  = outWil + M;
  float* outPlaq = outTop + M;

  char* ws = (char*)d_ws;
  const size_t MB = 1048576;
  unsigned short* hbuf    = (unsigned short*)(ws);              // [16384,2048] 64MB
  unsigned short* catbuf  = (unsigned short*)(ws + 64  * MB);   // [16384,2048] 64MB (w1)
  unsigned short* catT    = (unsigned short*)(ws + 192 * MB);   // [4096,4096]  32MB
  unsigned short* fw2T    = (unsigned short*)(ws + 224 * MB);   // [4096,2048]  16MB  \ contiguous =
  unsigned short* W2catT  = (unsigned short*)(ws + 240 * MB);   // [4096,2048]  16MB  / BTcat [8192,2048]
  unsigned short* BTcat   = fw2T;
  unsigned short* fw2bf   = (unsigned short*)(ws + 256 * MB);   // [2048,4096]  16MB
  unsigned short* ww2T    = (unsigned short*)(ws + 272 * MB);   // [1024,2048]  4MB
  float*          biascat = (float*)(ws + 276 * MB);            // [8192] 32KB

  const int SMEM = 131072;   // 4-slot ring (gemm256)
  (void)hipFuncSetAttribute((const void*)gemm256_kernel,
                            hipFuncAttributeMaxDynamicSharedMemorySize, SMEM);
  const int SMEM128 = 65536; // 4-slot ring of 16KB (gemm128b GEMM role)
  (void)hipFuncSetAttribute((const void*)gemm128b_kernel,
                            hipFuncAttributeMaxDynamicSharedMemorySize, SMEM128);

  // merged prep: fc1 + 3 transposes + cast + init heads + plaquette
  hipLaunchKernelGGL(prep_kernel, dim3(47169), dim3(256), 0, stream,
                     x, field, fw1, fb1, fw2, ww1, tw1, ww2, wb3, tb2,
                     hbuf, fw2T, catT, ww2T, fw2bf, outWil, outTop, outPlaq);

  // merged: W2catT GEMM (blocks 0..511) + biascat (blocks 512..2559)
  hipLaunchKernelGGL(gemm128b_kernel, dim3(2560), dim3(256), SMEM128, stream,
                     catT, fw2bf, W2catT, 2048, 4096, 32,
                     catT, fb2, wb1, tb1, biascat);

  // fused: C = h @ [fw2 | W2cat] + biascat   (M=16384, N=8192, K=2048)
  //   bn<16: field_output f32 (NT stores); 16<=bn<24: w1 relu bf16 (NB=2048);
  //   bn>=24: topology head fused (tw2 dot + atomicAdd outTop)
  hipLaunchKernelGGL(gemm256_kernel, dim3(64 * 32), dim3(512), SMEM, stream,
                     hbuf, BTcat, biascat, outF, catbuf, tw2, outTop,
                     2048, 2048, 4096, 2048, 16, 24, 64);

  // wilson: w2 = relu(w1 @ ww2 + wb2); outWil += w2 @ ww3  (all head blocks)
  hipLaunchKernelGGL(gemm256_kernel, dim3(64 * 4), dim3(512), SMEM, stream,
                     catbuf, ww2T, wb2, (float*)nullptr, (unsigned short*)nullptr,
                     ww3, outWil,
                     2048, 2048, 0, 0, 0, 0, 64);

  (void)in_sizes; (void)n_in; (void)out_size; (void)ws_size;
}